// Round 1
// baseline (5069.373 us; speedup 1.0000x reference)
//
#include <hip/hip_runtime.h>
#include <math.h>

#define NL 2
#define NH 32
#define NKVH 8
#define HD 64
#define DM 2048
#define FF 8192
#define SEQ 1024
#define RMS_EPS 1e-5f

// ---------------- embed gather ----------------
__global__ __launch_bounds__(256) void embed_kernel(const int* __restrict__ ids,
                                                    const float* __restrict__ emb,
                                                    float* __restrict__ x) {
    int s = blockIdx.x;
    int row = ids[s];
    const float4* src = (const float4*)(emb + (size_t)row * DM);
    float4* dst = (float4*)(x + (size_t)s * DM);
    #pragma unroll
    for (int i = 0; i < 2; ++i)
        dst[threadIdx.x + i * 256] = src[threadIdx.x + i * 256];
}

// ---------------- RMSNorm ----------------
__global__ __launch_bounds__(256) void rms_kernel(const float* __restrict__ x,
                                                  const float* __restrict__ g,
                                                  float* __restrict__ out) {
    int s = blockIdx.x;
    const float4* row = (const float4*)(x + (size_t)s * DM);
    float4 v0 = row[threadIdx.x * 2];
    float4 v1 = row[threadIdx.x * 2 + 1];
    float ss = v0.x*v0.x + v0.y*v0.y + v0.z*v0.z + v0.w*v0.w
             + v1.x*v1.x + v1.y*v1.y + v1.z*v1.z + v1.w*v1.w;
    #pragma unroll
    for (int o = 32; o > 0; o >>= 1) ss += __shfl_down(ss, o, 64);
    __shared__ float red[4];
    if ((threadIdx.x & 63) == 0) red[threadIdx.x >> 6] = ss;
    __syncthreads();
    float total = red[0] + red[1] + red[2] + red[3];
    float inv = 1.0f / sqrtf(total / (float)DM + RMS_EPS);
    const float4* g4 = (const float4*)g;
    float4 ga = g4[threadIdx.x * 2], gb = g4[threadIdx.x * 2 + 1];
    float4* o4 = (float4*)(out + (size_t)s * DM);
    float4 r0, r1;
    r0.x = v0.x * inv * ga.x; r0.y = v0.y * inv * ga.y;
    r0.z = v0.z * inv * ga.z; r0.w = v0.w * inv * ga.w;
    r1.x = v1.x * inv * gb.x; r1.y = v1.y * inv * gb.y;
    r1.z = v1.z * inv * gb.z; r1.w = v1.w * inv * gb.w;
    o4[threadIdx.x * 2] = r0;
    o4[threadIdx.x * 2 + 1] = r1;
}

// ---------------- f32 SGEMM: C[M,N] = A[M,K] @ W[K,N] (+C if accum) ----------------
#define BM 64
#define BN 64
#define BK 16
__global__ __launch_bounds__(256) void sgemm_kernel(const float* __restrict__ A,
                                                    const float* __restrict__ W,
                                                    float* __restrict__ C,
                                                    int M, int N, int K, int accum) {
    __shared__ float As[BK][BM];   // transposed A tile
    __shared__ float Bs[BK][BN];
    const int t = threadIdx.x;
    const int m0 = blockIdx.y * BM, n0 = blockIdx.x * BN;
    const int tr4 = (t >> 4) * 4, tc4 = (t & 15) * 4;
    const int arow = t >> 2, acol4 = (t & 3) * 4;   // A tile 64x16
    const int brow = t >> 4, bcol4 = (t & 15) * 4;  // W tile 16x64
    float acc[4][4];
    #pragma unroll
    for (int i = 0; i < 4; ++i)
        #pragma unroll
        for (int j = 0; j < 4; ++j) acc[i][j] = 0.f;

    for (int k0 = 0; k0 < K; k0 += BK) {
        float4 av = *(const float4*)(A + (size_t)(m0 + arow) * K + k0 + acol4);
        float4 bv = *(const float4*)(W + (size_t)(k0 + brow) * N + n0 + bcol4);
        __syncthreads();
        As[acol4 + 0][arow] = av.x;
        As[acol4 + 1][arow] = av.y;
        As[acol4 + 2][arow] = av.z;
        As[acol4 + 3][arow] = av.w;
        *(float4*)&Bs[brow][bcol4] = bv;
        __syncthreads();
        #pragma unroll
        for (int kk = 0; kk < BK; ++kk) {
            float4 a = *(const float4*)&As[kk][tr4];
            float4 b = *(const float4*)&Bs[kk][tc4];
            acc[0][0] += a.x*b.x; acc[0][1] += a.x*b.y; acc[0][2] += a.x*b.z; acc[0][3] += a.x*b.w;
            acc[1][0] += a.y*b.x; acc[1][1] += a.y*b.y; acc[1][2] += a.y*b.z; acc[1][3] += a.y*b.w;
            acc[2][0] += a.z*b.x; acc[2][1] += a.z*b.y; acc[2][2] += a.z*b.z; acc[2][3] += a.z*b.w;
            acc[3][0] += a.w*b.x; acc[3][1] += a.w*b.y; acc[3][2] += a.w*b.z; acc[3][3] += a.w*b.w;
        }
    }
    #pragma unroll
    for (int i = 0; i < 4; ++i) {
        float* crow = C + (size_t)(m0 + tr4 + i) * N + n0 + tc4;
        float4 o;
        if (accum) {
            float4 prev = *(const float4*)crow;
            o.x = prev.x + acc[i][0]; o.y = prev.y + acc[i][1];
            o.z = prev.z + acc[i][2]; o.w = prev.w + acc[i][3];
        } else {
            o.x = acc[i][0]; o.y = acc[i][1]; o.z = acc[i][2]; o.w = acc[i][3];
        }
        *(float4*)crow = o;
    }
}

// ---------------- RoPE (HF llama style), in place ----------------
__global__ __launch_bounds__(256) void rope_kernel(float* __restrict__ t, int nh, int total) {
    int idx = blockIdx.x * blockDim.x + threadIdx.x;  // total = SEQ*nh*32
    if (idx >= total) return;
    int i = idx & 31;
    int h = (idx >> 5) % nh;
    int s = idx / (32 * nh);
    float inv = powf(10000.0f, -(float)i / 32.0f);
    float ang = (float)s * inv;
    float c = cosf(ang), sn = sinf(ang);
    float* p = t + (size_t)s * nh * HD + h * HD + i;
    float a = p[0], b = p[32];
    p[0]  = a * c - b * sn;
    p[32] = b * c + a * sn;
}

// ---------------- causal GQA attention, flash-style f32 ----------------
#define APAD 68
__global__ __launch_bounds__(256) void attn_kernel(const float* __restrict__ q,
                                                   const float* __restrict__ k,
                                                   const float* __restrict__ v,
                                                   float* __restrict__ o) {
    __shared__ float Qs[64][APAD];
    __shared__ float Ks[64][APAD];
    __shared__ float Vs[64][APAD];
    const int t = threadIdx.x;
    const int h = blockIdx.y;
    const int kvh = h >> 2;
    const int qbase = blockIdx.x << 6;
    const int r = t >> 2, j = t & 3;
    const int lr = t >> 2, lc = (t & 3) * 16;
    {
        const float4* src = (const float4*)(q + (size_t)(qbase + lr) * (NH * HD) + h * HD + lc);
        #pragma unroll
        for (int u = 0; u < 4; ++u) *(float4*)&Qs[lr][lc + u * 4] = src[u];
    }
    float out[64];
    #pragma unroll
    for (int d = 0; d < 64; ++d) out[d] = 0.f;
    float m = -INFINITY, l = 0.f;
    const int qt = qbase >> 6;
    for (int kt = 0; kt <= qt; ++kt) {
        __syncthreads();
        {
            const float4* ksrc = (const float4*)(k + (size_t)(kt * 64 + lr) * (NKVH * HD) + kvh * HD + lc);
            const float4* vsrc = (const float4*)(v + (size_t)(kt * 64 + lr) * (NKVH * HD) + kvh * HD + lc);
            #pragma unroll
            for (int u = 0; u < 4; ++u) {
                *(float4*)&Ks[lr][lc + u * 4] = ksrc[u];
                *(float4*)&Vs[lr][lc + u * 4] = vsrc[u];
            }
        }
        __syncthreads();
        float sc[16];
        #pragma unroll
        for (int cc = 0; cc < 16; ++cc) sc[cc] = 0.f;
        #pragma unroll
        for (int d4 = 0; d4 < 16; ++d4) {
            float4 qv = *(const float4*)&Qs[r][d4 * 4];
            #pragma unroll
            for (int cc = 0; cc < 16; ++cc) {
                float4 kv = *(const float4*)&Ks[j * 16 + cc][d4 * 4];
                sc[cc] += qv.x*kv.x + qv.y*kv.y + qv.z*kv.z + qv.w*kv.w;
            }
        }
        float tmax = -INFINITY;
        #pragma unroll
        for (int cc = 0; cc < 16; ++cc) {
            sc[cc] *= 0.125f;
            int cg = kt * 64 + j * 16 + cc;
            if (cg > qbase + r) sc[cc] = -INFINITY;
            tmax = fmaxf(tmax, sc[cc]);
        }
        tmax = fmaxf(tmax, __shfl_xor(tmax, 1, 64));
        tmax = fmaxf(tmax, __shfl_xor(tmax, 2, 64));
        float mnew = fmaxf(m, tmax);
        float resc = expf(m - mnew);  // first iter: exp(-inf)=0
        float psum = 0.f;
        #pragma unroll
        for (int cc = 0; cc < 16; ++cc) {
            sc[cc] = expf(sc[cc] - mnew);
            psum += sc[cc];
        }
        l = l * resc + psum;
        m = mnew;
        #pragma unroll
        for (int d = 0; d < 64; ++d) out[d] *= resc;
        #pragma unroll
        for (int cc = 0; cc < 16; ++cc) {
            #pragma unroll
            for (int d4 = 0; d4 < 16; ++d4) {
                float4 vv = *(const float4*)&Vs[j * 16 + cc][d4 * 4];
                out[d4*4+0] += sc[cc] * vv.x;
                out[d4*4+1] += sc[cc] * vv.y;
                out[d4*4+2] += sc[cc] * vv.z;
                out[d4*4+3] += sc[cc] * vv.w;
            }
        }
    }
    #pragma unroll
    for (int d = 0; d < 64; ++d) {
        out[d] += __shfl_xor(out[d], 1, 64);
        out[d] += __shfl_xor(out[d], 2, 64);
    }
    l += __shfl_xor(l, 1, 64);
    l += __shfl_xor(l, 2, 64);
    if (j == 0) {
        float invl = 1.f / l;
        float* dst = o + (size_t)(qbase + r) * (NH * HD) + h * HD;
        #pragma unroll
        for (int d = 0; d < 64; ++d) dst[d] = out[d] * invl;
    }
}

// ---------------- silu(gate)*up -> gate ----------------
__global__ __launch_bounds__(256) void silu_mul_kernel(float* __restrict__ gate,
                                                       const float* __restrict__ up,
                                                       int n4) {
    int i = blockIdx.x * blockDim.x + threadIdx.x;
    int stride = gridDim.x * blockDim.x;
    for (; i < n4; i += stride) {
        float4 g = ((const float4*)gate)[i];
        float4 u = ((const float4*)up)[i];
        g.x = g.x / (1.f + expf(-g.x)) * u.x;
        g.y = g.y / (1.f + expf(-g.y)) * u.y;
        g.z = g.z / (1.f + expf(-g.z)) * u.z;
        g.w = g.w / (1.f + expf(-g.w)) * u.w;
        ((float4*)gate)[i] = g;
    }
}

extern "C" void kernel_launch(void* const* d_in, const int* in_sizes, int n_in,
                              void* d_out, int out_size, void* d_ws, size_t ws_size,
                              hipStream_t stream) {
    const int*   ids   = (const int*)d_in[0];
    const float* emb   = (const float*)d_in[1];
    const float* wq    = (const float*)d_in[2];
    const float* wk    = (const float*)d_in[3];
    const float* wv    = (const float*)d_in[4];
    const float* wo    = (const float*)d_in[5];
    const float* wgate = (const float*)d_in[6];
    const float* wup   = (const float*)d_in[7];
    const float* wdown = (const float*)d_in[8];
    const float* ln1   = (const float*)d_in[9];
    const float* ln2   = (const float*)d_in[10];
    float* x = (float*)d_out;

    float* h    = (float*)d_ws;
    float* qb   = h    + (size_t)SEQ * DM;
    float* kb   = qb   + (size_t)SEQ * DM;
    float* vb   = kb   + (size_t)SEQ * NKVH * HD;
    float* attn = vb   + (size_t)SEQ * NKVH * HD;
    float* gate = attn + (size_t)SEQ * DM;
    float* up   = gate + (size_t)SEQ * FF;

    embed_kernel<<<SEQ, 256, 0, stream>>>(ids, emb, x);

    for (int l = 0; l < NL; ++l) {
        const float* wq_l = wq + (size_t)l * DM * (NH * HD);
        const float* wk_l = wk + (size_t)l * DM * (NKVH * HD);
        const float* wv_l = wv + (size_t)l * DM * (NKVH * HD);
        const float* wo_l = wo + (size_t)l * (NH * HD) * DM;
        const float* wg_l = wgate + (size_t)l * DM * FF;
        const float* wu_l = wup   + (size_t)l * DM * FF;
        const float* wd_l = wdown + (size_t)l * FF * DM;

        rms_kernel<<<SEQ, 256, 0, stream>>>(x, ln1 + (size_t)l * DM, h);

        sgemm_kernel<<<dim3(DM / BN, SEQ / BM), 256, 0, stream>>>(h, wq_l, qb, SEQ, DM, DM, 0);
        sgemm_kernel<<<dim3((NKVH * HD) / BN, SEQ / BM), 256, 0, stream>>>(h, wk_l, kb, SEQ, NKVH * HD, DM, 0);
        sgemm_kernel<<<dim3((NKVH * HD) / BN, SEQ / BM), 256, 0, stream>>>(h, wv_l, vb, SEQ, NKVH * HD, DM, 0);

        rope_kernel<<<(SEQ * NH * 32 + 255) / 256, 256, 0, stream>>>(qb, NH, SEQ * NH * 32);
        rope_kernel<<<(SEQ * NKVH * 32 + 255) / 256, 256, 0, stream>>>(kb, NKVH, SEQ * NKVH * 32);

        attn_kernel<<<dim3(SEQ / 64, NH), 256, 0, stream>>>(qb, kb, vb, attn);

        sgemm_kernel<<<dim3(DM / BN, SEQ / BM), 256, 0, stream>>>(attn, wo_l, x, SEQ, DM, DM, 1);

        rms_kernel<<<SEQ, 256, 0, stream>>>(x, ln2 + (size_t)l * DM, h);

        sgemm_kernel<<<dim3(FF / BN, SEQ / BM), 256, 0, stream>>>(h, wg_l, gate, SEQ, FF, DM, 0);
        sgemm_kernel<<<dim3(FF / BN, SEQ / BM), 256, 0, stream>>>(h, wu_l, up, SEQ, FF, DM, 0);

        silu_mul_kernel<<<2048, 256, 0, stream>>>(gate, up, SEQ * FF / 4);

        sgemm_kernel<<<dim3(DM / BN, SEQ / BM), 256, 0, stream>>>(gate, wd_l, x, SEQ, DM, FF, 1);
    }
}

// Round 2
// 2089.928 us; speedup vs baseline: 2.4256x; 2.4256x over previous
//
#include <hip/hip_runtime.h>
#include <hip/hip_bf16.h>
#include <math.h>

#define NL 2
#define NH 32
#define NKVH 8
#define HD 64
#define DM 2048
#define FF 8192
#define SEQ 1024
#define QKVW 3072
#define RMS_EPS 1e-5f

typedef short s8v __attribute__((ext_vector_type(8)));
typedef short s4v __attribute__((ext_vector_type(4)));
typedef float f32x4 __attribute__((ext_vector_type(4)));
typedef __hip_bfloat16 bf16;

__device__ inline void gload16(const void* g, void* l) {
    __builtin_amdgcn_global_load_lds((const __attribute__((address_space(1))) void*)g,
                                     (__attribute__((address_space(3))) void*)l, 16, 0, 0);
}

// ---------------- weight transpose + f32->bf16: W[K][N] -> WT[N][K] ----------------
__global__ __launch_bounds__(256) void transpose_bf16_kernel(const float* __restrict__ W,
                                                             bf16* __restrict__ WT,
                                                             int K, int N) {
    __shared__ float tile[32][33];
    const int kb = blockIdx.y * 32, nb = blockIdx.x * 32;
    const int tx = threadIdx.x & 31, ty = threadIdx.x >> 5;
    #pragma unroll
    for (int i = 0; i < 4; ++i)
        tile[ty + i * 8][tx] = W[(size_t)(kb + ty + i * 8) * N + nb + tx];
    __syncthreads();
    #pragma unroll
    for (int i = 0; i < 4; ++i)
        WT[(size_t)(nb + ty + i * 8) * K + kb + tx] = __float2bfloat16(tile[tx][ty + i * 8]);
}

// ---------------- embed gather ----------------
__global__ __launch_bounds__(256) void embed_kernel(const int* __restrict__ ids,
                                                    const float* __restrict__ emb,
                                                    float* __restrict__ x) {
    int s = blockIdx.x;
    int row = ids[s];
    const float4* src = (const float4*)(emb + (size_t)row * DM);
    float4* dst = (float4*)(x + (size_t)s * DM);
    #pragma unroll
    for (int i = 0; i < 2; ++i)
        dst[threadIdx.x + i * 256] = src[threadIdx.x + i * 256];
}

// ---------------- RMSNorm: f32 in, bf16 out ----------------
__global__ __launch_bounds__(256) void rms_kernel(const float* __restrict__ x,
                                                  const float* __restrict__ g,
                                                  bf16* __restrict__ out) {
    int s = blockIdx.x;
    const float4* row = (const float4*)(x + (size_t)s * DM);
    float4 v0 = row[threadIdx.x * 2];
    float4 v1 = row[threadIdx.x * 2 + 1];
    float ss = v0.x*v0.x + v0.y*v0.y + v0.z*v0.z + v0.w*v0.w
             + v1.x*v1.x + v1.y*v1.y + v1.z*v1.z + v1.w*v1.w;
    #pragma unroll
    for (int o = 32; o > 0; o >>= 1) ss += __shfl_down(ss, o, 64);
    __shared__ float red[4];
    if ((threadIdx.x & 63) == 0) red[threadIdx.x >> 6] = ss;
    __syncthreads();
    float total = red[0] + red[1] + red[2] + red[3];
    float inv = 1.0f / sqrtf(total / (float)DM + RMS_EPS);
    const float4* g4 = (const float4*)g;
    float4 ga = g4[threadIdx.x * 2], gb = g4[threadIdx.x * 2 + 1];
    union { bf16 h[8]; s8v v; } u;
    u.h[0] = __float2bfloat16(v0.x * inv * ga.x);
    u.h[1] = __float2bfloat16(v0.y * inv * ga.y);
    u.h[2] = __float2bfloat16(v0.z * inv * ga.z);
    u.h[3] = __float2bfloat16(v0.w * inv * ga.w);
    u.h[4] = __float2bfloat16(v1.x * inv * gb.x);
    u.h[5] = __float2bfloat16(v1.y * inv * gb.y);
    u.h[6] = __float2bfloat16(v1.z * inv * gb.z);
    u.h[7] = __float2bfloat16(v1.w * inv * gb.w);
    *(s8v*)(out + (size_t)s * DM + threadIdx.x * 8) = u.v;
}

// ---------------- bf16 MFMA GEMM: C[M,N] = A[M,K] @ BT[N,K]^T (+C) ----------------
__global__ __launch_bounds__(256) void mfma_gemm_kernel(const bf16* __restrict__ A,
                                                        const bf16* __restrict__ BT,
                                                        float* __restrict__ C,
                                                        int M, int N, int K, int accum) {
    __shared__ bf16 As[128][32];
    __shared__ bf16 Bs[128][32];
    const int t = threadIdx.x;
    const int lane = t & 63, w = t >> 6;
    const int m0 = blockIdx.y * 128, n0 = blockIdx.x * 128;
    const int srow = w * 32 + (lane >> 2);
    const int scol = (lane & 3) * 8;
    const bf16* ap0 = A  + (size_t)(m0 + srow) * K + scol;
    const bf16* ap1 = ap0 + (size_t)16 * K;
    const bf16* bp0 = BT + (size_t)(n0 + srow) * K + scol;
    const bf16* bp1 = bp0 + (size_t)16 * K;
    char* lA0 = (char*)&As[0][0] + w * 2048 + lane * 16;
    char* lA1 = lA0 + 1024;
    char* lB0 = (char*)&Bs[0][0] + w * 2048 + lane * 16;
    char* lB1 = lB0 + 1024;
    const int wm = (w >> 1) * 64, wn = (w & 1) * 64;
    const int fr = lane & 15, ks = (lane >> 4) * 8;
    f32x4 acc[4][4];
    f32x4 z = {0.f, 0.f, 0.f, 0.f};
    #pragma unroll
    for (int i = 0; i < 4; ++i)
        #pragma unroll
        for (int j = 0; j < 4; ++j) acc[i][j] = z;

    for (int k0 = 0; k0 < K; k0 += 32) {
        __syncthreads();
        gload16(ap0 + k0, lA0);
        gload16(ap1 + k0, lA1);
        gload16(bp0 + k0, lB0);
        gload16(bp1 + k0, lB1);
        __syncthreads();
        s8v af[4], bfr[4];
        #pragma unroll
        for (int i = 0; i < 4; ++i) {
            af[i]  = *(const s8v*)&As[wm + i * 16 + fr][ks];
            bfr[i] = *(const s8v*)&Bs[wn + i * 16 + fr][ks];
        }
        #pragma unroll
        for (int i = 0; i < 4; ++i)
            #pragma unroll
            for (int j = 0; j < 4; ++j)
                acc[i][j] = __builtin_amdgcn_mfma_f32_16x16x32_bf16(af[i], bfr[j], acc[i][j], 0, 0, 0);
    }
    #pragma unroll
    for (int i = 0; i < 4; ++i) {
        #pragma unroll
        for (int j = 0; j < 4; ++j) {
            #pragma unroll
            for (int q = 0; q < 4; ++q) {
                int row = m0 + wm + i * 16 + (lane >> 4) * 4 + q;
                int col = n0 + wn + j * 16 + fr;
                float* p = C + (size_t)row * N + col;
                float vv = acc[i][j][q];
                if (accum) *p += vv; else *p = vv;
            }
        }
    }
}

// ---------------- RoPE on fused qkv buffer, in place ----------------
__global__ __launch_bounds__(256) void rope_kernel(float* __restrict__ t, int nh, int colbase, int total) {
    int idx = blockIdx.x * blockDim.x + threadIdx.x;
    if (idx >= total) return;
    int i = idx & 31;
    int hh = (idx >> 5) % nh;
    int s = idx / (32 * nh);
    float inv = powf(10000.0f, -(float)i / 32.0f);
    float ang = (float)s * inv;
    float c = cosf(ang), sn = sinf(ang);
    float* p = t + (size_t)s * QKVW + colbase + hh * HD + i;
    float a = p[0], b = p[32];
    p[0]  = a * c - b * sn;
    p[32] = b * c + a * sn;
}

// ---------------- causal GQA attention, f32 compute, bf16 out ----------------
#define APAD 68
__global__ __launch_bounds__(256) void attn_kernel(const float* __restrict__ qkv,
                                                   bf16* __restrict__ o) {
    __shared__ float Qs[64][APAD];
    __shared__ float Ks[64][APAD];
    __shared__ float Vs[64][APAD];
    const int t = threadIdx.x;
    const int h = blockIdx.y;
    const int kvh = h >> 2;
    const int qbase = blockIdx.x << 6;
    const int r = t >> 2, j = t & 3;
    const int lr = t >> 2, lc = (t & 3) * 16;
    {
        const float4* src = (const float4*)(qkv + (size_t)(qbase + lr) * QKVW + h * HD + lc);
        #pragma unroll
        for (int u = 0; u < 4; ++u) *(float4*)&Qs[lr][lc + u * 4] = src[u];
    }
    float out[64];
    #pragma unroll
    for (int d = 0; d < 64; ++d) out[d] = 0.f;
    float m = -INFINITY, l = 0.f;
    const int qt = qbase >> 6;
    for (int kt = 0; kt <= qt; ++kt) {
        __syncthreads();
        {
            const float4* ksrc = (const float4*)(qkv + (size_t)(kt * 64 + lr) * QKVW + DM + kvh * HD + lc);
            const float4* vsrc = (const float4*)(qkv + (size_t)(kt * 64 + lr) * QKVW + DM + 512 + kvh * HD + lc);
            #pragma unroll
            for (int u = 0; u < 4; ++u) {
                *(float4*)&Ks[lr][lc + u * 4] = ksrc[u];
                *(float4*)&Vs[lr][lc + u * 4] = vsrc[u];
            }
        }
        __syncthreads();
        float sc[16];
        #pragma unroll
        for (int cc = 0; cc < 16; ++cc) sc[cc] = 0.f;
        #pragma unroll
        for (int d4 = 0; d4 < 16; ++d4) {
            float4 qv = *(const float4*)&Qs[r][d4 * 4];
            #pragma unroll
            for (int cc = 0; cc < 16; ++cc) {
                float4 kv = *(const float4*)&Ks[j * 16 + cc][d4 * 4];
                sc[cc] += qv.x*kv.x + qv.y*kv.y + qv.z*kv.z + qv.w*kv.w;
            }
        }
        float tmax = -INFINITY;
        #pragma unroll
        for (int cc = 0; cc < 16; ++cc) {
            sc[cc] *= 0.125f;
            int cg = kt * 64 + j * 16 + cc;
            if (cg > qbase + r) sc[cc] = -INFINITY;
            tmax = fmaxf(tmax, sc[cc]);
        }
        tmax = fmaxf(tmax, __shfl_xor(tmax, 1, 64));
        tmax = fmaxf(tmax, __shfl_xor(tmax, 2, 64));
        float mnew = fmaxf(m, tmax);
        float resc = expf(m - mnew);
        float psum = 0.f;
        #pragma unroll
        for (int cc = 0; cc < 16; ++cc) {
            sc[cc] = expf(sc[cc] - mnew);
            psum += sc[cc];
        }
        l = l * resc + psum;
        m = mnew;
        #pragma unroll
        for (int d = 0; d < 64; ++d) out[d] *= resc;
        #pragma unroll
        for (int cc = 0; cc < 16; ++cc) {
            #pragma unroll
            for (int d4 = 0; d4 < 16; ++d4) {
                float4 vv = *(const float4*)&Vs[j * 16 + cc][d4 * 4];
                out[d4*4+0] += sc[cc] * vv.x;
                out[d4*4+1] += sc[cc] * vv.y;
                out[d4*4+2] += sc[cc] * vv.z;
                out[d4*4+3] += sc[cc] * vv.w;
            }
        }
    }
    #pragma unroll
    for (int d = 0; d < 64; ++d) {
        out[d] += __shfl_xor(out[d], 1, 64);
        out[d] += __shfl_xor(out[d], 2, 64);
    }
    l += __shfl_xor(l, 1, 64);
    l += __shfl_xor(l, 2, 64);
    if (j == 0) {
        float invl = 1.f / l;
        bf16* dst = o + (size_t)(qbase + r) * DM + h * HD;
        #pragma unroll
        for (int d4 = 0; d4 < 16; ++d4) {
            union { bf16 h4[4]; s4v v; } u;
            #pragma unroll
            for (int e = 0; e < 4; ++e) u.h4[e] = __float2bfloat16(out[d4 * 4 + e] * invl);
            *(s4v*)(dst + d4 * 4) = u.v;
        }
    }
}

// ---------------- silu(gate)*up from fused gu buffer -> bf16 ----------------
__global__ __launch_bounds__(256) void silu_mul_kernel(const float* __restrict__ gu,
                                                       bf16* __restrict__ ga) {
    const int n4 = SEQ * FF / 4;
    int i = blockIdx.x * blockDim.x + threadIdx.x;
    int stride = gridDim.x * blockDim.x;
    for (; i < n4; i += stride) {
        int s = i >> 11;          // FF/4 = 2048 groups per row
        int c4 = i & 2047;
        float4 g = *(const float4*)(gu + (size_t)s * (2 * FF) + c4 * 4);
        float4 u = *(const float4*)(gu + (size_t)s * (2 * FF) + FF + c4 * 4);
        union { bf16 h4[4]; s4v v; } o;
        o.h4[0] = __float2bfloat16(g.x / (1.f + expf(-g.x)) * u.x);
        o.h4[1] = __float2bfloat16(g.y / (1.f + expf(-g.y)) * u.y);
        o.h4[2] = __float2bfloat16(g.z / (1.f + expf(-g.z)) * u.z);
        o.h4[3] = __float2bfloat16(g.w / (1.f + expf(-g.w)) * u.w);
        *(s4v*)(ga + (size_t)s * FF + c4 * 4) = o.v;
    }
}

extern "C" void kernel_launch(void* const* d_in, const int* in_sizes, int n_in,
                              void* d_out, int out_size, void* d_ws, size_t ws_size,
                              hipStream_t stream) {
    const int*   ids   = (const int*)d_in[0];
    const float* emb   = (const float*)d_in[1];
    const float* wq    = (const float*)d_in[2];
    const float* wk    = (const float*)d_in[3];
    const float* wv    = (const float*)d_in[4];
    const float* wo    = (const float*)d_in[5];
    const float* wgate = (const float*)d_in[6];
    const float* wup   = (const float*)d_in[7];
    const float* wdown = (const float*)d_in[8];
    const float* ln1   = (const float*)d_in[9];
    const float* ln2   = (const float*)d_in[10];
    float* x = (float*)d_out;

    const size_t QKV_W = (size_t)QKVW * DM;
    const size_t O_W   = (size_t)DM * DM;
    const size_t GU_W  = (size_t)2 * FF * DM;
    const size_t D_W   = (size_t)DM * FF;

    bf16* wqkvT = (bf16*)d_ws;
    bf16* woT   = wqkvT + 2 * QKV_W;
    bf16* wguT  = woT   + 2 * O_W;
    bf16* wdT   = wguT  + 2 * GU_W;
    bf16* h_bf  = wdT   + 2 * D_W;
    bf16* attnb = h_bf  + (size_t)SEQ * DM;
    bf16* gab   = attnb + (size_t)SEQ * DM;
    float* qkv  = (float*)(gab + (size_t)SEQ * FF);
    float* gu   = qkv + (size_t)SEQ * QKVW;

    auto T = [&](const float* src, bf16* dst, int K_, int N_) {
        transpose_bf16_kernel<<<dim3(N_ / 32, K_ / 32), 256, 0, stream>>>(src, dst, K_, N_);
    };
    auto G = [&](const bf16* A_, const bf16* B_, float* C_, int M_, int N_, int K_, int acc_) {
        mfma_gemm_kernel<<<dim3(N_ / 128, M_ / 128), 256, 0, stream>>>(A_, B_, C_, M_, N_, K_, acc_);
    };

    // weight convert+transpose (once per call)
    for (int l = 0; l < NL; ++l) {
        T(wq + (size_t)l * DM * DM,        wqkvT + l * QKV_W,                 DM, DM);
        T(wk + (size_t)l * DM * 512,       wqkvT + l * QKV_W + (size_t)DM * DM,   DM, 512);
        T(wv + (size_t)l * DM * 512,       wqkvT + l * QKV_W + (size_t)2560 * DM, DM, 512);
        T(wo + (size_t)l * DM * DM,        woT + l * O_W,                     DM, DM);
        T(wgate + (size_t)l * DM * FF,     wguT + l * GU_W,                   DM, FF);
        T(wup + (size_t)l * DM * FF,       wguT + l * GU_W + (size_t)FF * DM, DM, FF);
        T(wdown + (size_t)l * FF * DM,     wdT + l * D_W,                     FF, DM);
    }

    embed_kernel<<<SEQ, 256, 0, stream>>>(ids, emb, x);

    for (int l = 0; l < NL; ++l) {
        rms_kernel<<<SEQ, 256, 0, stream>>>(x, ln1 + (size_t)l * DM, h_bf);

        G(h_bf, wqkvT + l * QKV_W, qkv, SEQ, QKVW, DM, 0);

        rope_kernel<<<(SEQ * NH * 32 + 255) / 256, 256, 0, stream>>>(qkv, NH, 0, SEQ * NH * 32);
        rope_kernel<<<(SEQ * NKVH * 32 + 255) / 256, 256, 0, stream>>>(qkv, NKVH, DM, SEQ * NKVH * 32);

        attn_kernel<<<dim3(SEQ / 64, NH), 256, 0, stream>>>(qkv, attnb);

        G(attnb, woT + l * O_W, x, SEQ, DM, DM, 1);

        rms_kernel<<<SEQ, 256, 0, stream>>>(x, ln2 + (size_t)l * DM, h_bf);

        G(h_bf, wguT + l * GU_W, gu, SEQ, 2 * FF, DM, 0);

        silu_mul_kernel<<<2048, 256, 0, stream>>>(gu, gab);

        G(gab, wdT + l * D_W, x, SEQ, DM, FF, 1);
    }
}

// Round 3
// 1225.039 us; speedup vs baseline: 4.1381x; 1.7060x over previous
//
#include <hip/hip_runtime.h>
#include <hip/hip_bf16.h>
#include <math.h>

#define NL 2
#define NH 32
#define NKVH 8
#define HD 64
#define DM 2048
#define FF 8192
#define SEQ 1024
#define QKVW 3072
#define RMS_EPS 1e-5f

typedef short s8v __attribute__((ext_vector_type(8)));
typedef short s4v __attribute__((ext_vector_type(4)));
typedef float f32x4 __attribute__((ext_vector_type(4)));
typedef __hip_bfloat16 bf16;

__device__ inline void gload16(const void* g, void* l) {
    __builtin_amdgcn_global_load_lds((const __attribute__((address_space(1))) void*)g,
                                     (__attribute__((address_space(3))) void*)l, 16, 0, 0);
}

// ---------------- weight transpose + f32->bf16: W[K][N] -> WT[N][K] ----------------
__global__ __launch_bounds__(256) void transpose_bf16_kernel(const float* __restrict__ W,
                                                             bf16* __restrict__ WT,
                                                             int K, int N) {
    __shared__ float tile[32][33];
    const int kb = blockIdx.y * 32, nb = blockIdx.x * 32;
    const int tx = threadIdx.x & 31, ty = threadIdx.x >> 5;
    #pragma unroll
    for (int i = 0; i < 4; ++i)
        tile[ty + i * 8][tx] = W[(size_t)(kb + ty + i * 8) * N + nb + tx];
    __syncthreads();
    #pragma unroll
    for (int i = 0; i < 4; ++i)
        WT[(size_t)(nb + ty + i * 8) * K + kb + tx] = __float2bfloat16(tile[tx][ty + i * 8]);
}

// ---------------- embed gather ----------------
__global__ __launch_bounds__(256) void embed_kernel(const int* __restrict__ ids,
                                                    const float* __restrict__ emb,
                                                    float* __restrict__ x) {
    int s = blockIdx.x;
    int row = ids[s];
    const float4* src = (const float4*)(emb + (size_t)row * DM);
    float4* dst = (float4*)(x + (size_t)s * DM);
    #pragma unroll
    for (int i = 0; i < 2; ++i)
        dst[threadIdx.x + i * 256] = src[threadIdx.x + i * 256];
}

// ---------------- RMSNorm: f32 in, bf16 out ----------------
__global__ __launch_bounds__(256) void rms_kernel(const float* __restrict__ x,
                                                  const float* __restrict__ g,
                                                  bf16* __restrict__ out) {
    int s = blockIdx.x;
    const float4* row = (const float4*)(x + (size_t)s * DM);
    float4 v0 = row[threadIdx.x * 2];
    float4 v1 = row[threadIdx.x * 2 + 1];
    float ss = v0.x*v0.x + v0.y*v0.y + v0.z*v0.z + v0.w*v0.w
             + v1.x*v1.x + v1.y*v1.y + v1.z*v1.z + v1.w*v1.w;
    #pragma unroll
    for (int o = 32; o > 0; o >>= 1) ss += __shfl_down(ss, o, 64);
    __shared__ float red[4];
    if ((threadIdx.x & 63) == 0) red[threadIdx.x >> 6] = ss;
    __syncthreads();
    float total = red[0] + red[1] + red[2] + red[3];
    float inv = 1.0f / sqrtf(total / (float)DM + RMS_EPS);
    const float4* g4 = (const float4*)g;
    float4 ga = g4[threadIdx.x * 2], gb = g4[threadIdx.x * 2 + 1];
    union { bf16 h[8]; s8v v; } u;
    u.h[0] = __float2bfloat16(v0.x * inv * ga.x);
    u.h[1] = __float2bfloat16(v0.y * inv * ga.y);
    u.h[2] = __float2bfloat16(v0.z * inv * ga.z);
    u.h[3] = __float2bfloat16(v0.w * inv * ga.w);
    u.h[4] = __float2bfloat16(v1.x * inv * gb.x);
    u.h[5] = __float2bfloat16(v1.y * inv * gb.y);
    u.h[6] = __float2bfloat16(v1.z * inv * gb.z);
    u.h[7] = __float2bfloat16(v1.w * inv * gb.w);
    *(s8v*)(out + (size_t)s * DM + threadIdx.x * 8) = u.v;
}

// ---------------- bf16 MFMA GEMM: C[M,N] = A[M,K] @ BT[N,K]^T (+C) ----------------
__global__ __launch_bounds__(256) void mfma_gemm_kernel(const bf16* __restrict__ A,
                                                        const bf16* __restrict__ BT,
                                                        float* __restrict__ C,
                                                        int M, int N, int K, int accum) {
    __shared__ bf16 As[128][32];
    __shared__ bf16 Bs[128][32];
    const int t = threadIdx.x;
    const int lane = t & 63, w = t >> 6;
    const int m0 = blockIdx.y * 128, n0 = blockIdx.x * 128;
    const int srow = w * 32 + (lane >> 2);
    const int scol = (lane & 3) * 8;
    const bf16* ap0 = A  + (size_t)(m0 + srow) * K + scol;
    const bf16* ap1 = ap0 + (size_t)16 * K;
    const bf16* bp0 = BT + (size_t)(n0 + srow) * K + scol;
    const bf16* bp1 = bp0 + (size_t)16 * K;
    char* lA0 = (char*)&As[0][0] + w * 2048 + lane * 16;
    char* lA1 = lA0 + 1024;
    char* lB0 = (char*)&Bs[0][0] + w * 2048 + lane * 16;
    char* lB1 = lB0 + 1024;
    const int wm = (w >> 1) * 64, wn = (w & 1) * 64;
    const int fr = lane & 15, ks = (lane >> 4) * 8;
    f32x4 acc[4][4];
    f32x4 z = {0.f, 0.f, 0.f, 0.f};
    #pragma unroll
    for (int i = 0; i < 4; ++i)
        #pragma unroll
        for (int j = 0; j < 4; ++j) acc[i][j] = z;

    for (int k0 = 0; k0 < K; k0 += 32) {
        __syncthreads();
        gload16(ap0 + k0, lA0);
        gload16(ap1 + k0, lA1);
        gload16(bp0 + k0, lB0);
        gload16(bp1 + k0, lB1);
        __syncthreads();
        s8v af[4], bfr[4];
        #pragma unroll
        for (int i = 0; i < 4; ++i) {
            af[i]  = *(const s8v*)&As[wm + i * 16 + fr][ks];
            bfr[i] = *(const s8v*)&Bs[wn + i * 16 + fr][ks];
        }
        #pragma unroll
        for (int i = 0; i < 4; ++i)
            #pragma unroll
            for (int j = 0; j < 4; ++j)
                acc[i][j] = __builtin_amdgcn_mfma_f32_16x16x32_bf16(af[i], bfr[j], acc[i][j], 0, 0, 0);
    }
    #pragma unroll
    for (int i = 0; i < 4; ++i) {
        #pragma unroll
        for (int j = 0; j < 4; ++j) {
            #pragma unroll
            for (int q = 0; q < 4; ++q) {
                int row = m0 + wm + i * 16 + (lane >> 4) * 4 + q;
                int col = n0 + wn + j * 16 + fr;
                float* p = C + (size_t)row * N + col;
                float vv = acc[i][j][q];
                if (accum) *p += vv; else *p = vv;
            }
        }
    }
}

// ---------------- RoPE: f32 qkv -> bf16 Qh[h][s][d], Kh[kvh][s][d] ----------------
__global__ __launch_bounds__(256) void rope_qk_kernel(const float* __restrict__ qkv,
                                                      bf16* __restrict__ Qh,
                                                      bf16* __restrict__ Kh) {
    int idx = blockIdx.x * 256 + threadIdx.x;   // SEQ*(NH+NKVH)*32 threads
    int i = idx & 31;
    int hh = (idx >> 5) % (NH + NKVH);
    int s = idx / (32 * (NH + NKVH));
    bool isq = hh < NH;
    int col = isq ? hh * HD + i : DM + (hh - NH) * HD + i;
    float a = qkv[(size_t)s * QKVW + col];
    float b = qkv[(size_t)s * QKVW + col + 32];
    float inv = exp2f(-(float)i * 0.41524101186092029f);  // log2(10000)/32
    float ang = (float)s * inv;
    float c = cosf(ang), sn = sinf(ang);
    float ra = a * c - b * sn;
    float rb = b * c + a * sn;
    if (isq) {
        bf16* p = Qh + ((size_t)hh * SEQ + s) * HD + i;
        p[0]  = __float2bfloat16(ra);
        p[32] = __float2bfloat16(rb);
    } else {
        bf16* p = Kh + ((size_t)(hh - NH) * SEQ + s) * HD + i;
        p[0]  = __float2bfloat16(ra);
        p[32] = __float2bfloat16(rb);
    }
}

// ---------------- V transpose: f32 qkv -> bf16 Vt[kvh][d][s] ----------------
__global__ __launch_bounds__(256) void vtrans_kernel(const float* __restrict__ qkv,
                                                     bf16* __restrict__ Vt) {
    __shared__ float tile[64][65];
    const int s0 = blockIdx.x * 64;
    const int kvh = blockIdx.y;
    const int tx = threadIdx.x & 63, ty = threadIdx.x >> 6;
    #pragma unroll
    for (int i = 0; i < 16; ++i)
        tile[i * 4 + ty][tx] = qkv[(size_t)(s0 + i * 4 + ty) * QKVW + DM + 512 + kvh * HD + tx];
    __syncthreads();
    #pragma unroll
    for (int i = 0; i < 16; ++i) {
        int d = i * 4 + ty;
        Vt[((size_t)kvh * HD + d) * SEQ + s0 + tx] = __float2bfloat16(tile[tx][d]);
    }
}

// ---------------- MFMA flash attention: 4 waves x 16-row strips, KVBLK=64 ----------------
__global__ __launch_bounds__(256) void attn_mfma_kernel(const bf16* __restrict__ Qh,
                                                        const bf16* __restrict__ Kh,
                                                        const bf16* __restrict__ Vt,
                                                        bf16* __restrict__ o) {
    __shared__ char lds[32768];
    char* Qs = lds;              // 64 q rows x 128B, swizzled
    char* Ks = lds + 8192;       // 64 key rows x 128B
    char* Vs = lds + 16384;      // 64 d rows x 128B (V^T tile)
    char* Ps = lds + 24576;      // 64 q rows x 128B (P tile)
    const int t = threadIdx.x, lane = t & 63, w = t >> 6;
    const int g = lane >> 4, lo = lane & 15;
    const int h = blockIdx.y, kvh = h >> 2;
    const int qbase = blockIdx.x * 64;
    const int strip = w * 16;
    const bf16* qsrc = Qh + ((size_t)h * SEQ + qbase) * HD;
    const bf16* ksrc = Kh + (size_t)kvh * SEQ * HD;
    const bf16* vsrc = Vt + (size_t)kvh * HD * SEQ;

    // stage Q tile (swizzled)
    #pragma unroll
    for (int c = t; c < 512; c += 256) {
        int row = c >> 3, col = c & 7;
        *(s8v*)(Qs + row * 128 + ((col * 16) ^ ((row & 7) << 4))) =
            *(const s8v*)(qsrc + row * HD + col * 8);
    }

    f32x4 oacc[4];
    f32x4 z = {0.f, 0.f, 0.f, 0.f};
    #pragma unroll
    for (int dj = 0; dj < 4; ++dj) oacc[dj] = z;
    float m0[4], lsum[4];
    #pragma unroll
    for (int r = 0; r < 4; ++r) { m0[r] = -INFINITY; lsum[r] = 0.f; }

    const int qt = blockIdx.x;
    for (int kt = 0; kt <= qt; ++kt) {
        __syncthreads();
        const bf16* kq = ksrc + (size_t)(kt * 64) * HD;
        const bf16* vq = vsrc + kt * 64;
        #pragma unroll
        for (int c = t; c < 512; c += 256) {
            int row = c >> 3, col = c & 7;
            int swz = (col * 16) ^ ((row & 7) << 4);
            *(s8v*)(Ks + row * 128 + swz) = *(const s8v*)(kq + row * HD + col * 8);
            *(s8v*)(Vs + row * 128 + swz) = *(const s8v*)(vq + (size_t)row * SEQ + col * 8);
        }
        __syncthreads();

        // S = Q K^T for this wave's strip
        s8v qa0 = *(const s8v*)(Qs + (strip + lo) * 128 + ((g * 16) ^ ((lo & 7) << 4)));
        s8v qa1 = *(const s8v*)(Qs + (strip + lo) * 128 + ((64 + g * 16) ^ ((lo & 7) << 4)));
        f32x4 sacc[4];
        #pragma unroll
        for (int j = 0; j < 4; ++j) {
            s8v kb0 = *(const s8v*)(Ks + (j * 16 + lo) * 128 + ((g * 16) ^ ((lo & 7) << 4)));
            s8v kb1 = *(const s8v*)(Ks + (j * 16 + lo) * 128 + ((64 + g * 16) ^ ((lo & 7) << 4)));
            f32x4 sv = __builtin_amdgcn_mfma_f32_16x16x32_bf16(qa0, kb0, z, 0, 0, 0);
            sacc[j] = __builtin_amdgcn_mfma_f32_16x16x32_bf16(qa1, kb1, sv, 0, 0, 0);
        }
        // scale + causal mask
        #pragma unroll
        for (int j = 0; j < 4; ++j) {
            int kgl = kt * 64 + j * 16 + lo;
            #pragma unroll
            for (int r = 0; r < 4; ++r) {
                int qgl = qbase + strip + g * 4 + r;
                float sv = sacc[j][r] * 0.125f;
                sacc[j][r] = (kgl <= qgl) ? sv : -INFINITY;
            }
        }
        // online softmax
        float rmax[4], resc[4];
        #pragma unroll
        for (int r = 0; r < 4; ++r) {
            float mx = fmaxf(fmaxf(sacc[0][r], sacc[1][r]), fmaxf(sacc[2][r], sacc[3][r]));
            mx = fmaxf(mx, __shfl_xor(mx, 1, 64));
            mx = fmaxf(mx, __shfl_xor(mx, 2, 64));
            mx = fmaxf(mx, __shfl_xor(mx, 4, 64));
            mx = fmaxf(mx, __shfl_xor(mx, 8, 64));
            float mn = fmaxf(m0[r], mx);
            resc[r] = expf(m0[r] - mn);
            m0[r] = mn;
            rmax[r] = mn;
        }
        #pragma unroll
        for (int j = 0; j < 4; ++j)
            #pragma unroll
            for (int r = 0; r < 4; ++r)
                sacc[j][r] = expf(sacc[j][r] - rmax[r]);
        #pragma unroll
        for (int r = 0; r < 4; ++r) {
            float ps = sacc[0][r] + sacc[1][r] + sacc[2][r] + sacc[3][r];
            lsum[r] = lsum[r] * resc[r] + ps;
        }
        #pragma unroll
        for (int dj = 0; dj < 4; ++dj)
            #pragma unroll
            for (int r = 0; r < 4; ++r)
                oacc[dj][r] *= resc[r];
        // P -> LDS (wave-local strip, swizzled)
        #pragma unroll
        for (int j = 0; j < 4; ++j) {
            #pragma unroll
            for (int r = 0; r < 4; ++r) {
                int prow = strip + g * 4 + r;
                int pcol = j * 16 + lo;
                *(bf16*)(Ps + prow * 128 + ((pcol * 2) ^ ((prow & 7) << 4))) =
                    __float2bfloat16(sacc[j][r]);
            }
        }
        // PV
        s8v pa0 = *(const s8v*)(Ps + (strip + lo) * 128 + ((g * 16) ^ ((lo & 7) << 4)));
        s8v pa1 = *(const s8v*)(Ps + (strip + lo) * 128 + ((64 + g * 16) ^ ((lo & 7) << 4)));
        #pragma unroll
        for (int dj = 0; dj < 4; ++dj) {
            s8v vb0 = *(const s8v*)(Vs + (dj * 16 + lo) * 128 + ((g * 16) ^ ((lo & 7) << 4)));
            s8v vb1 = *(const s8v*)(Vs + (dj * 16 + lo) * 128 + ((64 + g * 16) ^ ((lo & 7) << 4)));
            oacc[dj] = __builtin_amdgcn_mfma_f32_16x16x32_bf16(pa0, vb0, oacc[dj], 0, 0, 0);
            oacc[dj] = __builtin_amdgcn_mfma_f32_16x16x32_bf16(pa1, vb1, oacc[dj], 0, 0, 0);
        }
    }
    // epilogue
    float invl[4];
    #pragma unroll
    for (int r = 0; r < 4; ++r) {
        float l = lsum[r];
        l += __shfl_xor(l, 1, 64);
        l += __shfl_xor(l, 2, 64);
        l += __shfl_xor(l, 4, 64);
        l += __shfl_xor(l, 8, 64);
        invl[r] = 1.f / l;
    }
    #pragma unroll
    for (int dj = 0; dj < 4; ++dj) {
        #pragma unroll
        for (int r = 0; r < 4; ++r) {
            int qrow = qbase + strip + g * 4 + r;
            o[(size_t)qrow * DM + h * HD + dj * 16 + lo] =
                __float2bfloat16(oacc[dj][r] * invl[r]);
        }
    }
}

// ---------------- silu(gate)*up from fused gu buffer -> bf16 ----------------
__global__ __launch_bounds__(256) void silu_mul_kernel(const float* __restrict__ gu,
                                                       bf16* __restrict__ ga) {
    const int n4 = SEQ * FF / 4;
    int i = blockIdx.x * blockDim.x + threadIdx.x;
    int stride = gridDim.x * blockDim.x;
    for (; i < n4; i += stride) {
        int s = i >> 11;
        int c4 = i & 2047;
        float4 g = *(const float4*)(gu + (size_t)s * (2 * FF) + c4 * 4);
        float4 u = *(const float4*)(gu + (size_t)s * (2 * FF) + FF + c4 * 4);
        union { bf16 h4[4]; s4v v; } o;
        o.h4[0] = __float2bfloat16(g.x / (1.f + expf(-g.x)) * u.x);
        o.h4[1] = __float2bfloat16(g.y / (1.f + expf(-g.y)) * u.y);
        o.h4[2] = __float2bfloat16(g.z / (1.f + expf(-g.z)) * u.z);
        o.h4[3] = __float2bfloat16(g.w / (1.f + expf(-g.w)) * u.w);
        *(s4v*)(ga + (size_t)s * FF + c4 * 4) = o.v;
    }
}

extern "C" void kernel_launch(void* const* d_in, const int* in_sizes, int n_in,
                              void* d_out, int out_size, void* d_ws, size_t ws_size,
                              hipStream_t stream) {
    const int*   ids   = (const int*)d_in[0];
    const float* emb   = (const float*)d_in[1];
    const float* wq    = (const float*)d_in[2];
    const float* wk    = (const float*)d_in[3];
    const float* wv    = (const float*)d_in[4];
    const float* wo    = (const float*)d_in[5];
    const float* wgate = (const float*)d_in[6];
    const float* wup   = (const float*)d_in[7];
    const float* wdown = (const float*)d_in[8];
    const float* ln1   = (const float*)d_in[9];
    const float* ln2   = (const float*)d_in[10];
    float* x = (float*)d_out;

    const size_t QKV_W = (size_t)QKVW * DM;
    const size_t O_W   = (size_t)DM * DM;
    const size_t GU_W  = (size_t)2 * FF * DM;
    const size_t D_W   = (size_t)DM * FF;

    bf16* wqkvT = (bf16*)d_ws;
    bf16* woT   = wqkvT + 2 * QKV_W;
    bf16* wguT  = woT   + 2 * O_W;
    bf16* wdT   = wguT  + 2 * GU_W;
    bf16* h_bf  = wdT   + 2 * D_W;
    bf16* attnb = h_bf  + (size_t)SEQ * DM;
    bf16* gab   = attnb + (size_t)SEQ * DM;
    bf16* Qhb   = gab   + (size_t)SEQ * FF;
    bf16* Khb   = Qhb   + (size_t)NH * SEQ * HD;
    bf16* Vtb   = Khb   + (size_t)NKVH * SEQ * HD;
    float* qkv  = (float*)(Vtb + (size_t)NKVH * HD * SEQ);
    float* gu   = qkv + (size_t)SEQ * QKVW;

    auto T = [&](const float* src, bf16* dst, int K_, int N_) {
        transpose_bf16_kernel<<<dim3(N_ / 32, K_ / 32), 256, 0, stream>>>(src, dst, K_, N_);
    };
    auto G = [&](const bf16* A_, const bf16* B_, float* C_, int M_, int N_, int K_, int acc_) {
        mfma_gemm_kernel<<<dim3(N_ / 128, M_ / 128), 256, 0, stream>>>(A_, B_, C_, M_, N_, K_, acc_);
    };

    for (int l = 0; l < NL; ++l) {
        T(wq + (size_t)l * DM * DM,        wqkvT + l * QKV_W,                 DM, DM);
        T(wk + (size_t)l * DM * 512,       wqkvT + l * QKV_W + (size_t)DM * DM,   DM, 512);
        T(wv + (size_t)l * DM * 512,       wqkvT + l * QKV_W + (size_t)2560 * DM, DM, 512);
        T(wo + (size_t)l * DM * DM,        woT + l * O_W,                     DM, DM);
        T(wgate + (size_t)l * DM * FF,     wguT + l * GU_W,                   DM, FF);
        T(wup + (size_t)l * DM * FF,       wguT + l * GU_W + (size_t)FF * DM, DM, FF);
        T(wdown + (size_t)l * FF * DM,     wdT + l * D_W,                     FF, DM);
    }

    embed_kernel<<<SEQ, 256, 0, stream>>>(ids, emb, x);

    for (int l = 0; l < NL; ++l) {
        rms_kernel<<<SEQ, 256, 0, stream>>>(x, ln1 + (size_t)l * DM, h_bf);

        G(h_bf, wqkvT + l * QKV_W, qkv, SEQ, QKVW, DM, 0);

        rope_qk_kernel<<<(SEQ * (NH + NKVH) * 32) / 256, 256, 0, stream>>>(qkv, Qhb, Khb);
        vtrans_kernel<<<dim3(SEQ / 64, NKVH), 256, 0, stream>>>(qkv, Vtb);

        attn_mfma_kernel<<<dim3(SEQ / 64, NH), 256, 0, stream>>>(Qhb, Khb, Vtb, attnb);

        G(attnb, woT + l * O_W, x, SEQ, DM, DM, 1);

        rms_kernel<<<SEQ, 256, 0, stream>>>(x, ln2 + (size_t)l * DM, h_bf);

        G(h_bf, wguT + l * GU_W, gu, SEQ, 2 * FF, DM, 0);

        silu_mul_kernel<<<2048, 256, 0, stream>>>(gu, gab);

        G(gab, wdT + l * D_W, x, SEQ, DM, FF, 1);
    }
}

// Round 4
// 974.483 us; speedup vs baseline: 5.2021x; 1.2571x over previous
//
#include <hip/hip_runtime.h>
#include <hip/hip_bf16.h>
#include <math.h>

#define NL 2
#define NH 32
#define NKVH 8
#define HD 64
#define DM 2048
#define FF 8192
#define SEQ 1024
#define QKVW 3072
#define RMS_EPS 1e-5f

typedef short s8v __attribute__((ext_vector_type(8)));
typedef short s4v __attribute__((ext_vector_type(4)));
typedef float f32x4 __attribute__((ext_vector_type(4)));
typedef __hip_bfloat16 bf16;

__device__ inline void gload16(const void* g, void* l) {
    __builtin_amdgcn_global_load_lds((const __attribute__((address_space(1))) void*)g,
                                     (__attribute__((address_space(3))) void*)l, 16, 0, 0);
}

// ---------------- weight transpose + f32->bf16: W[K][N] -> WT[N][K], 64x64 tiles ----------------
__global__ __launch_bounds__(256) void transpose_bf16_kernel(const float* __restrict__ W,
                                                             bf16* __restrict__ WT,
                                                             int K, int N) {
    __shared__ float tile[64][68];   // [n][k], padded row (272B, 16B-aligned)
    const int kb = blockIdx.y * 64, nb = blockIdx.x * 64;
    const int t = threadIdx.x;
    const int tk = t >> 4;           // 0..15
    const int tn4 = t & 15;          // float4 column group
    #pragma unroll
    for (int i = 0; i < 4; ++i) {
        float4 v = *(const float4*)(W + (size_t)(kb + tk + i * 16) * N + nb + tn4 * 4);
        tile[tn4 * 4 + 0][tk + i * 16] = v.x;
        tile[tn4 * 4 + 1][tk + i * 16] = v.y;
        tile[tn4 * 4 + 2][tk + i * 16] = v.z;
        tile[tn4 * 4 + 3][tk + i * 16] = v.w;
    }
    __syncthreads();
    const int wn = t >> 4, wk4 = t & 15;
    #pragma unroll
    for (int i = 0; i < 4; ++i) {
        float4 v = *(const float4*)&tile[wn + i * 16][wk4 * 4];
        union { bf16 h4[4]; s4v s; } u;
        u.h4[0] = __float2bfloat16(v.x);
        u.h4[1] = __float2bfloat16(v.y);
        u.h4[2] = __float2bfloat16(v.z);
        u.h4[3] = __float2bfloat16(v.w);
        *(s4v*)(WT + (size_t)(nb + wn + i * 16) * K + kb + wk4 * 4) = u.s;
    }
}

// ---------------- embed gather ----------------
__global__ __launch_bounds__(256) void embed_kernel(const int* __restrict__ ids,
                                                    const float* __restrict__ emb,
                                                    float* __restrict__ x) {
    int s = blockIdx.x;
    int row = ids[s];
    const float4* src = (const float4*)(emb + (size_t)row * DM);
    float4* dst = (float4*)(x + (size_t)s * DM);
    #pragma unroll
    for (int i = 0; i < 2; ++i)
        dst[threadIdx.x + i * 256] = src[threadIdx.x + i * 256];
}

// ---------------- RMSNorm: f32 in, bf16 out ----------------
__global__ __launch_bounds__(256) void rms_kernel(const float* __restrict__ x,
                                                  const float* __restrict__ g,
                                                  bf16* __restrict__ out) {
    int s = blockIdx.x;
    const float4* row = (const float4*)(x + (size_t)s * DM);
    float4 v0 = row[threadIdx.x * 2];
    float4 v1 = row[threadIdx.x * 2 + 1];
    float ss = v0.x*v0.x + v0.y*v0.y + v0.z*v0.z + v0.w*v0.w
             + v1.x*v1.x + v1.y*v1.y + v1.z*v1.z + v1.w*v1.w;
    #pragma unroll
    for (int o = 32; o > 0; o >>= 1) ss += __shfl_down(ss, o, 64);
    __shared__ float red[4];
    if ((threadIdx.x & 63) == 0) red[threadIdx.x >> 6] = ss;
    __syncthreads();
    float total = red[0] + red[1] + red[2] + red[3];
    float inv = 1.0f / sqrtf(total / (float)DM + RMS_EPS);
    const float4* g4 = (const float4*)g;
    float4 ga = g4[threadIdx.x * 2], gb = g4[threadIdx.x * 2 + 1];
    union { bf16 h[8]; s8v v; } u;
    u.h[0] = __float2bfloat16(v0.x * inv * ga.x);
    u.h[1] = __float2bfloat16(v0.y * inv * ga.y);
    u.h[2] = __float2bfloat16(v0.z * inv * ga.z);
    u.h[3] = __float2bfloat16(v0.w * inv * ga.w);
    u.h[4] = __float2bfloat16(v1.x * inv * gb.x);
    u.h[5] = __float2bfloat16(v1.y * inv * gb.y);
    u.h[6] = __float2bfloat16(v1.z * inv * gb.z);
    u.h[7] = __float2bfloat16(v1.w * inv * gb.w);
    *(s8v*)(out + (size_t)s * DM + threadIdx.x * 8) = u.v;
}

// ---------------- bf16 MFMA GEMM, 2-phase double-buffered ----------------
// C[M,N] = A[M,K] @ BT[N,K]^T (+C). BM=128, BK=32, BN template (128 or 64).
template<int BN>
__global__ __launch_bounds__(256) void mfma_gemm_kernel(const bf16* __restrict__ A,
                                                        const bf16* __restrict__ BT,
                                                        float* __restrict__ C,
                                                        int M, int N, int K, int accum) {
    constexpr int MI = (BN == 128) ? 4 : 2;
    __shared__ bf16 As[2][128 * 32];
    __shared__ bf16 Bs[2][BN * 32];
    const int t = threadIdx.x;
    const int lane = t & 63, w = t >> 6;
    const int m0 = blockIdx.y * 128, n0 = blockIdx.x * BN;
    const int srow = w * 32 + (lane >> 2);
    const int scol = (lane & 3) * 8;
    const bf16* ap0 = A + (size_t)(m0 + srow) * K + scol;
    const bf16* ap1 = ap0 + (size_t)16 * K;
    const bf16* bp0;
    const bf16* bp1 = nullptr;
    if constexpr (BN == 128) {
        bp0 = BT + (size_t)(n0 + srow) * K + scol;
        bp1 = bp0 + (size_t)16 * K;
    } else {
        bp0 = BT + (size_t)(n0 + (t >> 2)) * K + (t & 3) * 8;
    }
    const int wm = (BN == 128) ? (w >> 1) * 64 : w * 32;
    const int wn = (BN == 128) ? (w & 1) * 64 : 0;
    const int fr = lane & 15, ks = (lane >> 4) * 8;

    f32x4 acc[MI][4];
    f32x4 z = {0.f, 0.f, 0.f, 0.f};
    #pragma unroll
    for (int i = 0; i < MI; ++i)
        #pragma unroll
        for (int j = 0; j < 4; ++j) acc[i][j] = z;

    auto stage = [&](int buf, int k0) {
        char* lA = (char*)&As[buf][0] + w * 2048 + lane * 16;
        gload16(ap0 + k0, lA);
        gload16(ap1 + k0, lA + 1024);
        if constexpr (BN == 128) {
            char* lB = (char*)&Bs[buf][0] + w * 2048 + lane * 16;
            gload16(bp0 + k0, lB);
            gload16(bp1 + k0, lB + 1024);
        } else {
            char* lB = (char*)&Bs[buf][0] + w * 1024 + lane * 16;
            gload16(bp0 + k0, lB);
        }
    };

    stage(0, 0);
    __syncthreads();
    const int nt = K / 32;
    int cur = 0;
    for (int tt = 0; tt < nt; ++tt) {
        if (tt + 1 < nt) stage(cur ^ 1, (tt + 1) * 32);
        const bf16* Ab = &As[cur][0];
        const bf16* Bb = &Bs[cur][0];
        s8v af[MI], bfr[4];
        #pragma unroll
        for (int i = 0; i < MI; ++i)
            af[i] = *(const s8v*)(Ab + (wm + i * 16 + fr) * 32 + ks);
        #pragma unroll
        for (int j = 0; j < 4; ++j)
            bfr[j] = *(const s8v*)(Bb + (wn + j * 16 + fr) * 32 + ks);
        #pragma unroll
        for (int i = 0; i < MI; ++i)
            #pragma unroll
            for (int j = 0; j < 4; ++j)
                acc[i][j] = __builtin_amdgcn_mfma_f32_16x16x32_bf16(af[i], bfr[j], acc[i][j], 0, 0, 0);
        __syncthreads();   // drains vmcnt (prefetch landed) + protects dbuf reuse
        cur ^= 1;
    }
    #pragma unroll
    for (int i = 0; i < MI; ++i) {
        #pragma unroll
        for (int j = 0; j < 4; ++j) {
            #pragma unroll
            for (int q = 0; q < 4; ++q) {
                int row = m0 + wm + i * 16 + (lane >> 4) * 4 + q;
                int col = n0 + wn + j * 16 + fr;
                float* p = C + (size_t)row * N + col;
                float vv = acc[i][j][q];
                if (accum) *p += vv; else *p = vv;
            }
        }
    }
}

// ---------------- RoPE: f32 qkv -> bf16 Qh[h][s][d], Kh[kvh][s][d] ----------------
__global__ __launch_bounds__(256) void rope_qk_kernel(const float* __restrict__ qkv,
                                                      bf16* __restrict__ Qh,
                                                      bf16* __restrict__ Kh) {
    int idx = blockIdx.x * 256 + threadIdx.x;   // SEQ*(NH+NKVH)*32 threads
    int i = idx & 31;
    int hh = (idx >> 5) % (NH + NKVH);
    int s = idx / (32 * (NH + NKVH));
    bool isq = hh < NH;
    int col = isq ? hh * HD + i : DM + (hh - NH) * HD + i;
    float a = qkv[(size_t)s * QKVW + col];
    float b = qkv[(size_t)s * QKVW + col + 32];
    float inv = exp2f(-(float)i * 0.41524101186092029f);  // log2(10000)/32
    float ang = (float)s * inv;
    float c = cosf(ang), sn = sinf(ang);
    float ra = a * c - b * sn;
    float rb = b * c + a * sn;
    if (isq) {
        bf16* p = Qh + ((size_t)hh * SEQ + s) * HD + i;
        p[0]  = __float2bfloat16(ra);
        p[32] = __float2bfloat16(rb);
    } else {
        bf16* p = Kh + ((size_t)(hh - NH) * SEQ + s) * HD + i;
        p[0]  = __float2bfloat16(ra);
        p[32] = __float2bfloat16(rb);
    }
}

// ---------------- V transpose: f32 qkv -> bf16 Vt[kvh][d][s] ----------------
__global__ __launch_bounds__(256) void vtrans_kernel(const float* __restrict__ qkv,
                                                     bf16* __restrict__ Vt) {
    __shared__ float tile[64][65];
    const int s0 = blockIdx.x * 64;
    const int kvh = blockIdx.y;
    const int tx = threadIdx.x & 63, ty = threadIdx.x >> 6;
    #pragma unroll
    for (int i = 0; i < 16; ++i)
        tile[i * 4 + ty][tx] = qkv[(size_t)(s0 + i * 4 + ty) * QKVW + DM + 512 + kvh * HD + tx];
    __syncthreads();
    #pragma unroll
    for (int i = 0; i < 16; ++i) {
        int d = i * 4 + ty;
        Vt[((size_t)kvh * HD + d) * SEQ + s0 + tx] = __float2bfloat16(tile[tx][d]);
    }
}

// ---------------- MFMA flash attention: 4 waves x 16-row strips, KVBLK=64 ----------------
__global__ __launch_bounds__(256) void attn_mfma_kernel(const bf16* __restrict__ Qh,
                                                        const bf16* __restrict__ Kh,
                                                        const bf16* __restrict__ Vt,
                                                        bf16* __restrict__ o) {
    __shared__ char lds[32768];
    char* Qs = lds;
    char* Ks = lds + 8192;
    char* Vs = lds + 16384;
    char* Ps = lds + 24576;
    const int t = threadIdx.x, lane = t & 63, w = t >> 6;
    const int g = lane >> 4, lo = lane & 15;
    const int h = blockIdx.y, kvh = h >> 2;
    const int qbase = blockIdx.x * 64;
    const int strip = w * 16;
    const bf16* qsrc = Qh + ((size_t)h * SEQ + qbase) * HD;
    const bf16* ksrc = Kh + (size_t)kvh * SEQ * HD;
    const bf16* vsrc = Vt + (size_t)kvh * HD * SEQ;

    #pragma unroll
    for (int c = t; c < 512; c += 256) {
        int row = c >> 3, col = c & 7;
        *(s8v*)(Qs + row * 128 + ((col * 16) ^ ((row & 7) << 4))) =
            *(const s8v*)(qsrc + row * HD + col * 8);
    }

    f32x4 oacc[4];
    f32x4 z = {0.f, 0.f, 0.f, 0.f};
    #pragma unroll
    for (int dj = 0; dj < 4; ++dj) oacc[dj] = z;
    float m0[4], lsum[4];
    #pragma unroll
    for (int r = 0; r < 4; ++r) { m0[r] = -INFINITY; lsum[r] = 0.f; }

    const int qt = blockIdx.x;
    for (int kt = 0; kt <= qt; ++kt) {
        __syncthreads();
        const bf16* kq = ksrc + (size_t)(kt * 64) * HD;
        const bf16* vq = vsrc + kt * 64;
        #pragma unroll
        for (int c = t; c < 512; c += 256) {
            int row = c >> 3, col = c & 7;
            int swz = (col * 16) ^ ((row & 7) << 4);
            *(s8v*)(Ks + row * 128 + swz) = *(const s8v*)(kq + row * HD + col * 8);
            *(s8v*)(Vs + row * 128 + swz) = *(const s8v*)(vq + (size_t)row * SEQ + col * 8);
        }
        __syncthreads();

        s8v qa0 = *(const s8v*)(Qs + (strip + lo) * 128 + ((g * 16) ^ ((lo & 7) << 4)));
        s8v qa1 = *(const s8v*)(Qs + (strip + lo) * 128 + ((64 + g * 16) ^ ((lo & 7) << 4)));
        f32x4 sacc[4];
        #pragma unroll
        for (int j = 0; j < 4; ++j) {
            s8v kb0 = *(const s8v*)(Ks + (j * 16 + lo) * 128 + ((g * 16) ^ ((lo & 7) << 4)));
            s8v kb1 = *(const s8v*)(Ks + (j * 16 + lo) * 128 + ((64 + g * 16) ^ ((lo & 7) << 4)));
            f32x4 sv = __builtin_amdgcn_mfma_f32_16x16x32_bf16(qa0, kb0, z, 0, 0, 0);
            sacc[j] = __builtin_amdgcn_mfma_f32_16x16x32_bf16(qa1, kb1, sv, 0, 0, 0);
        }
        #pragma unroll
        for (int j = 0; j < 4; ++j) {
            int kgl = kt * 64 + j * 16 + lo;
            #pragma unroll
            for (int r = 0; r < 4; ++r) {
                int qgl = qbase + strip + g * 4 + r;
                float sv = sacc[j][r] * 0.125f;
                sacc[j][r] = (kgl <= qgl) ? sv : -INFINITY;
            }
        }
        float rmax[4], resc[4];
        #pragma unroll
        for (int r = 0; r < 4; ++r) {
            float mx = fmaxf(fmaxf(sacc[0][r], sacc[1][r]), fmaxf(sacc[2][r], sacc[3][r]));
            mx = fmaxf(mx, __shfl_xor(mx, 1, 64));
            mx = fmaxf(mx, __shfl_xor(mx, 2, 64));
            mx = fmaxf(mx, __shfl_xor(mx, 4, 64));
            mx = fmaxf(mx, __shfl_xor(mx, 8, 64));
            float mn = fmaxf(m0[r], mx);
            resc[r] = expf(m0[r] - mn);
            m0[r] = mn;
            rmax[r] = mn;
        }
        #pragma unroll
        for (int j = 0; j < 4; ++j)
            #pragma unroll
            for (int r = 0; r < 4; ++r)
                sacc[j][r] = expf(sacc[j][r] - rmax[r]);
        #pragma unroll
        for (int r = 0; r < 4; ++r) {
            float ps = sacc[0][r] + sacc[1][r] + sacc[2][r] + sacc[3][r];
            lsum[r] = lsum[r] * resc[r] + ps;
        }
        #pragma unroll
        for (int dj = 0; dj < 4; ++dj)
            #pragma unroll
            for (int r = 0; r < 4; ++r)
                oacc[dj][r] *= resc[r];
        #pragma unroll
        for (int j = 0; j < 4; ++j) {
            #pragma unroll
            for (int r = 0; r < 4; ++r) {
                int prow = strip + g * 4 + r;
                int pcol = j * 16 + lo;
                *(bf16*)(Ps + prow * 128 + ((pcol * 2) ^ ((prow & 7) << 4))) =
                    __float2bfloat16(sacc[j][r]);
            }
        }
        s8v pa0 = *(const s8v*)(Ps + (strip + lo) * 128 + ((g * 16) ^ ((lo & 7) << 4)));
        s8v pa1 = *(const s8v*)(Ps + (strip + lo) * 128 + ((64 + g * 16) ^ ((lo & 7) << 4)));
        #pragma unroll
        for (int dj = 0; dj < 4; ++dj) {
            s8v vb0 = *(const s8v*)(Vs + (dj * 16 + lo) * 128 + ((g * 16) ^ ((lo & 7) << 4)));
            s8v vb1 = *(const s8v*)(Vs + (dj * 16 + lo) * 128 + ((64 + g * 16) ^ ((lo & 7) << 4)));
            oacc[dj] = __builtin_amdgcn_mfma_f32_16x16x32_bf16(pa0, vb0, oacc[dj], 0, 0, 0);
            oacc[dj] = __builtin_amdgcn_mfma_f32_16x16x32_bf16(pa1, vb1, oacc[dj], 0, 0, 0);
        }
    }
    float invl[4];
    #pragma unroll
    for (int r = 0; r < 4; ++r) {
        float l = lsum[r];
        l += __shfl_xor(l, 1, 64);
        l += __shfl_xor(l, 2, 64);
        l += __shfl_xor(l, 4, 64);
        l += __shfl_xor(l, 8, 64);
        invl[r] = 1.f / l;
    }
    #pragma unroll
    for (int dj = 0; dj < 4; ++dj) {
        #pragma unroll
        for (int r = 0; r < 4; ++r) {
            int qrow = qbase + strip + g * 4 + r;
            o[(size_t)qrow * DM + h * HD + dj * 16 + lo] =
                __float2bfloat16(oacc[dj][r] * invl[r]);
        }
    }
}

// ---------------- silu(gate)*up from fused gu buffer -> bf16 ----------------
__global__ __launch_bounds__(256) void silu_mul_kernel(const float* __restrict__ gu,
                                                       bf16* __restrict__ ga) {
    const int n4 = SEQ * FF / 4;
    int i = blockIdx.x * blockDim.x + threadIdx.x;
    int stride = gridDim.x * blockDim.x;
    for (; i < n4; i += stride) {
        int s = i >> 11;
        int c4 = i & 2047;
        float4 g = *(const float4*)(gu + (size_t)s * (2 * FF) + c4 * 4);
        float4 u = *(const float4*)(gu + (size_t)s * (2 * FF) + FF + c4 * 4);
        union { bf16 h4[4]; s4v v; } o;
        o.h4[0] = __float2bfloat16(g.x / (1.f + expf(-g.x)) * u.x);
        o.h4[1] = __float2bfloat16(g.y / (1.f + expf(-g.y)) * u.y);
        o.h4[2] = __float2bfloat16(g.z / (1.f + expf(-g.z)) * u.z);
        o.h4[3] = __float2bfloat16(g.w / (1.f + expf(-g.w)) * u.w);
        *(s4v*)(ga + (size_t)s * FF + c4 * 4) = o.v;
    }
}

extern "C" void kernel_launch(void* const* d_in, const int* in_sizes, int n_in,
                              void* d_out, int out_size, void* d_ws, size_t ws_size,
                              hipStream_t stream) {
    const int*   ids   = (const int*)d_in[0];
    const float* emb   = (const float*)d_in[1];
    const float* wq    = (const float*)d_in[2];
    const float* wk    = (const float*)d_in[3];
    const float* wv    = (const float*)d_in[4];
    const float* wo    = (const float*)d_in[5];
    const float* wgate = (const float*)d_in[6];
    const float* wup   = (const float*)d_in[7];
    const float* wdown = (const float*)d_in[8];
    const float* ln1   = (const float*)d_in[9];
    const float* ln2   = (const float*)d_in[10];
    float* x = (float*)d_out;

    const size_t QKV_W = (size_t)QKVW * DM;
    const size_t O_W   = (size_t)DM * DM;
    const size_t GU_W  = (size_t)2 * FF * DM;
    const size_t D_W   = (size_t)DM * FF;

    bf16* wqkvT = (bf16*)d_ws;
    bf16* woT   = wqkvT + 2 * QKV_W;
    bf16* wguT  = woT   + 2 * O_W;
    bf16* wdT   = wguT  + 2 * GU_W;
    bf16* h_bf  = wdT   + 2 * D_W;
    bf16* attnb = h_bf  + (size_t)SEQ * DM;
    bf16* gab   = attnb + (size_t)SEQ * DM;
    bf16* Qhb   = gab   + (size_t)SEQ * FF;
    bf16* Khb   = Qhb   + (size_t)NH * SEQ * HD;
    bf16* Vtb   = Khb   + (size_t)NKVH * SEQ * HD;
    float* qkv  = (float*)(Vtb + (size_t)NKVH * HD * SEQ);
    float* gu   = qkv + (size_t)SEQ * QKVW;

    auto T = [&](const float* src, bf16* dst, int K_, int N_) {
        transpose_bf16_kernel<<<dim3(N_ / 64, K_ / 64), 256, 0, stream>>>(src, dst, K_, N_);
    };
    auto G128 = [&](const bf16* A_, const bf16* B_, float* C_, int M_, int N_, int K_, int acc_) {
        mfma_gemm_kernel<128><<<dim3(N_ / 128, M_ / 128), 256, 0, stream>>>(A_, B_, C_, M_, N_, K_, acc_);
    };
    auto G64 = [&](const bf16* A_, const bf16* B_, float* C_, int M_, int N_, int K_, int acc_) {
        mfma_gemm_kernel<64><<<dim3(N_ / 64, M_ / 128), 256, 0, stream>>>(A_, B_, C_, M_, N_, K_, acc_);
    };

    for (int l = 0; l < NL; ++l) {
        T(wq + (size_t)l * DM * DM,        wqkvT + l * QKV_W,                 DM, DM);
        T(wk + (size_t)l * DM * 512,       wqkvT + l * QKV_W + (size_t)DM * DM,   DM, 512);
        T(wv + (size_t)l * DM * 512,       wqkvT + l * QKV_W + (size_t)2560 * DM, DM, 512);
        T(wo + (size_t)l * DM * DM,        woT + l * O_W,                     DM, DM);
        T(wgate + (size_t)l * DM * FF,     wguT + l * GU_W,                   DM, FF);
        T(wup + (size_t)l * DM * FF,       wguT + l * GU_W + (size_t)FF * DM, DM, FF);
        T(wdown + (size_t)l * FF * DM,     wdT + l * D_W,                     FF, DM);
    }

    embed_kernel<<<SEQ, 256, 0, stream>>>(ids, emb, x);

    for (int l = 0; l < NL; ++l) {
        rms_kernel<<<SEQ, 256, 0, stream>>>(x, ln1 + (size_t)l * DM, h_bf);

        G64(h_bf, wqkvT + l * QKV_W, qkv, SEQ, QKVW, DM, 0);

        rope_qk_kernel<<<(SEQ * (NH + NKVH) * 32) / 256, 256, 0, stream>>>(qkv, Qhb, Khb);
        vtrans_kernel<<<dim3(SEQ / 64, NKVH), 256, 0, stream>>>(qkv, Vtb);

        attn_mfma_kernel<<<dim3(SEQ / 64, NH), 256, 0, stream>>>(Qhb, Khb, Vtb, attnb);

        G64(attnb, woT + l * O_W, x, SEQ, DM, DM, 1);

        rms_kernel<<<SEQ, 256, 0, stream>>>(x, ln2 + (size_t)l * DM, h_bf);

        G128(h_bf, wguT + l * GU_W, gu, SEQ, 2 * FF, DM, 0);

        silu_mul_kernel<<<2048, 256, 0, stream>>>(gu, gab);

        G64(gab, wdT + l * D_W, x, SEQ, DM, FF, 1);
    }
}

// Round 5
// 813.790 us; speedup vs baseline: 6.2293x; 1.1975x over previous
//
#include <hip/hip_runtime.h>
#include <hip/hip_bf16.h>
#include <math.h>

#define NL 2
#define NH 32
#define NKVH 8
#define HD 64
#define DM 2048
#define FF 8192
#define SEQ 1024
#define QKVW 3072
#define RMS_EPS 1e-5f

typedef short s8v __attribute__((ext_vector_type(8)));
typedef short s4v __attribute__((ext_vector_type(4)));
typedef float f32x4 __attribute__((ext_vector_type(4)));
typedef __hip_bfloat16 bf16;

__device__ inline void gload16(const void* g, void* l) {
    __builtin_amdgcn_global_load_lds((const __attribute__((address_space(1))) void*)g,
                                     (__attribute__((address_space(3))) void*)l, 16, 0, 0);
}

// ---------------- weight transpose + f32->bf16: W[K][N] -> WT[N][K], 64x64 tiles ----------------
__global__ __launch_bounds__(256) void transpose_bf16_kernel(const float* __restrict__ W,
                                                             bf16* __restrict__ WT,
                                                             int K, int N) {
    __shared__ float tile[64][68];
    const int kb = blockIdx.y * 64, nb = blockIdx.x * 64;
    const int t = threadIdx.x;
    const int tk = t >> 4;
    const int tn4 = t & 15;
    #pragma unroll
    for (int i = 0; i < 4; ++i) {
        float4 v = *(const float4*)(W + (size_t)(kb + tk + i * 16) * N + nb + tn4 * 4);
        tile[tn4 * 4 + 0][tk + i * 16] = v.x;
        tile[tn4 * 4 + 1][tk + i * 16] = v.y;
        tile[tn4 * 4 + 2][tk + i * 16] = v.z;
        tile[tn4 * 4 + 3][tk + i * 16] = v.w;
    }
    __syncthreads();
    const int wn = t >> 4, wk4 = t & 15;
    #pragma unroll
    for (int i = 0; i < 4; ++i) {
        float4 v = *(const float4*)&tile[wn + i * 16][wk4 * 4];
        union { bf16 h4[4]; s4v s; } u;
        u.h4[0] = __float2bfloat16(v.x);
        u.h4[1] = __float2bfloat16(v.y);
        u.h4[2] = __float2bfloat16(v.z);
        u.h4[3] = __float2bfloat16(v.w);
        *(s4v*)(WT + (size_t)(nb + wn + i * 16) * K + kb + wk4 * 4) = u.s;
    }
}

// ---------------- embed gather ----------------
__global__ __launch_bounds__(256) void embed_kernel(const int* __restrict__ ids,
                                                    const float* __restrict__ emb,
                                                    float* __restrict__ x) {
    int s = blockIdx.x;
    int row = ids[s];
    const float4* src = (const float4*)(emb + (size_t)row * DM);
    float4* dst = (float4*)(x + (size_t)s * DM);
    #pragma unroll
    for (int i = 0; i < 2; ++i)
        dst[threadIdx.x + i * 256] = src[threadIdx.x + i * 256];
}

// ---------------- RMSNorm: f32 in, bf16 out ----------------
__global__ __launch_bounds__(256) void rms_kernel(const float* __restrict__ x,
                                                  const float* __restrict__ g,
                                                  bf16* __restrict__ out) {
    int s = blockIdx.x;
    const float4* row = (const float4*)(x + (size_t)s * DM);
    float4 v0 = row[threadIdx.x * 2];
    float4 v1 = row[threadIdx.x * 2 + 1];
    float ss = v0.x*v0.x + v0.y*v0.y + v0.z*v0.z + v0.w*v0.w
             + v1.x*v1.x + v1.y*v1.y + v1.z*v1.z + v1.w*v1.w;
    #pragma unroll
    for (int o = 32; o > 0; o >>= 1) ss += __shfl_down(ss, o, 64);
    __shared__ float red[4];
    if ((threadIdx.x & 63) == 0) red[threadIdx.x >> 6] = ss;
    __syncthreads();
    float total = red[0] + red[1] + red[2] + red[3];
    float inv = 1.0f / sqrtf(total / (float)DM + RMS_EPS);
    const float4* g4 = (const float4*)g;
    float4 ga = g4[threadIdx.x * 2], gb = g4[threadIdx.x * 2 + 1];
    union { bf16 h[8]; s8v v; } u;
    u.h[0] = __float2bfloat16(v0.x * inv * ga.x);
    u.h[1] = __float2bfloat16(v0.y * inv * ga.y);
    u.h[2] = __float2bfloat16(v0.z * inv * ga.z);
    u.h[3] = __float2bfloat16(v0.w * inv * ga.w);
    u.h[4] = __float2bfloat16(v1.x * inv * gb.x);
    u.h[5] = __float2bfloat16(v1.y * inv * gb.y);
    u.h[6] = __float2bfloat16(v1.z * inv * gb.z);
    u.h[7] = __float2bfloat16(v1.w * inv * gb.w);
    *(s8v*)(out + (size_t)s * DM + threadIdx.x * 8) = u.v;
}

// ---------------- bf16 MFMA GEMM, 3-buffer depth-2 pipeline, counted vmcnt ----------------
// C[M,N] = A[M,K] @ BT[N,K]^T. BM=BN=128, BK=32. blockIdx.z = K-chunk (split-K partials).
template<bool OUTBF>
__global__ __launch_bounds__(256) void mfma_gemm_kernel(const bf16* __restrict__ A,
                                                        const bf16* __restrict__ BT,
                                                        float* __restrict__ C,
                                                        bf16* __restrict__ Cb,
                                                        int M, int N, int Kstride,
                                                        int Kchunk, int accum) {
    __shared__ bf16 As[3][128 * 32];
    __shared__ bf16 Bs[3][128 * 32];
    const int t = threadIdx.x;
    const int lane = t & 63, w = t >> 6;
    const int m0 = blockIdx.y * 128, n0 = blockIdx.x * 128;
    const size_t koff = (size_t)blockIdx.z * Kchunk;
    const int srow = w * 32 + (lane >> 2);
    const int scol = (lane & 3) * 8;
    const bf16* ap0 = A + (size_t)(m0 + srow) * Kstride + koff + scol;
    const bf16* ap1 = ap0 + (size_t)16 * Kstride;
    const bf16* bp0 = BT + (size_t)(n0 + srow) * Kstride + koff + scol;
    const bf16* bp1 = bp0 + (size_t)16 * Kstride;
    float* Cz = C + (size_t)blockIdx.z * M * N;
    const int wm = (w >> 1) * 64, wn = (w & 1) * 64;
    const int fr = lane & 15, ks = (lane >> 4) * 8;

    f32x4 acc[4][4];
    f32x4 z = {0.f, 0.f, 0.f, 0.f};
    #pragma unroll
    for (int i = 0; i < 4; ++i)
        #pragma unroll
        for (int j = 0; j < 4; ++j) acc[i][j] = z;

    auto stage = [&](int buf, int k0) {
        char* lA = (char*)&As[buf][0] + w * 2048 + lane * 16;
        gload16(ap0 + k0, lA);
        gload16(ap1 + k0, lA + 1024);
        char* lB = (char*)&Bs[buf][0] + w * 2048 + lane * 16;
        gload16(bp0 + k0, lB);
        gload16(bp1 + k0, lB + 1024);
    };

    const int nt = Kchunk / 32;
    stage(0, 0);
    if (nt > 1) stage(1, 32);

    int bcur = 0;
    for (int tt = 0; tt < nt; ++tt) {
        if (tt + 1 < nt) { asm volatile("s_waitcnt vmcnt(4)" ::: "memory"); }
        else             { asm volatile("s_waitcnt vmcnt(0)" ::: "memory"); }
        __builtin_amdgcn_s_barrier();
        __builtin_amdgcn_sched_barrier(0);
        if (tt + 2 < nt) {
            int bstage = (bcur == 0) ? 2 : bcur - 1;   // (tt+2) % 3
            stage(bstage, (tt + 2) * 32);
        }
        const bf16* Ab = &As[bcur][0];
        const bf16* Bb = &Bs[bcur][0];
        s8v af[4], bfr[4];
        #pragma unroll
        for (int i = 0; i < 4; ++i)
            af[i] = *(const s8v*)(Ab + (wm + i * 16 + fr) * 32 + ks);
        #pragma unroll
        for (int j = 0; j < 4; ++j)
            bfr[j] = *(const s8v*)(Bb + (wn + j * 16 + fr) * 32 + ks);
        #pragma unroll
        for (int i = 0; i < 4; ++i)
            #pragma unroll
            for (int j = 0; j < 4; ++j)
                acc[i][j] = __builtin_amdgcn_mfma_f32_16x16x32_bf16(af[i], bfr[j], acc[i][j], 0, 0, 0);
        bcur = (bcur == 2) ? 0 : bcur + 1;
    }

    #pragma unroll
    for (int i = 0; i < 4; ++i) {
        #pragma unroll
        for (int j = 0; j < 4; ++j) {
            #pragma unroll
            for (int q = 0; q < 4; ++q) {
                int row = m0 + wm + i * 16 + (lane >> 4) * 4 + q;
                int col = n0 + wn + j * 16 + fr;
                float vv = acc[i][j][q];
                if constexpr (OUTBF) {
                    Cb[(size_t)row * N + col] = __float2bfloat16(vv);
                } else {
                    float* p = Cz + (size_t)row * N + col;
                    if (accum) *p += vv; else *p = vv;
                }
            }
        }
    }
}

// ---------------- split-K reduce: x += p0+p1+p2+p3 ----------------
__global__ __launch_bounds__(256) void reduce4_kernel(float* __restrict__ x,
                                                      const float* __restrict__ p) {
    const int n4 = SEQ * DM / 4;
    int i = blockIdx.x * 256 + threadIdx.x;
    if (i >= n4) return;
    float4 a = ((const float4*)x)[i];
    #pragma unroll
    for (int c = 0; c < 4; ++c) {
        float4 v = ((const float4*)p)[i + c * n4];
        a.x += v.x; a.y += v.y; a.z += v.z; a.w += v.w;
    }
    ((float4*)x)[i] = a;
}

// ---------------- RoPE: f32 qkv -> bf16 Qh[h][s][d], Kh[kvh][s][d] ----------------
__global__ __launch_bounds__(256) void rope_qk_kernel(const float* __restrict__ qkv,
                                                      bf16* __restrict__ Qh,
                                                      bf16* __restrict__ Kh) {
    int idx = blockIdx.x * 256 + threadIdx.x;
    int i = idx & 31;
    int hh = (idx >> 5) % (NH + NKVH);
    int s = idx / (32 * (NH + NKVH));
    bool isq = hh < NH;
    int col = isq ? hh * HD + i : DM + (hh - NH) * HD + i;
    float a = qkv[(size_t)s * QKVW + col];
    float b = qkv[(size_t)s * QKVW + col + 32];
    float inv = exp2f(-(float)i * 0.41524101186092029f);
    float ang = (float)s * inv;
    float c = cosf(ang), sn = sinf(ang);
    float ra = a * c - b * sn;
    float rb = b * c + a * sn;
    if (isq) {
        bf16* p = Qh + ((size_t)hh * SEQ + s) * HD + i;
        p[0]  = __float2bfloat16(ra);
        p[32] = __float2bfloat16(rb);
    } else {
        bf16* p = Kh + ((size_t)(hh - NH) * SEQ + s) * HD + i;
        p[0]  = __float2bfloat16(ra);
        p[32] = __float2bfloat16(rb);
    }
}

// ---------------- V transpose: f32 qkv -> bf16 Vt[kvh][d][s] ----------------
__global__ __launch_bounds__(256) void vtrans_kernel(const float* __restrict__ qkv,
                                                     bf16* __restrict__ Vt) {
    __shared__ float tile[64][65];
    const int s0 = blockIdx.x * 64;
    const int kvh = blockIdx.y;
    const int tx = threadIdx.x & 63, ty = threadIdx.x >> 6;
    #pragma unroll
    for (int i = 0; i < 16; ++i)
        tile[i * 4 + ty][tx] = qkv[(size_t)(s0 + i * 4 + ty) * QKVW + DM + 512 + kvh * HD + tx];
    __syncthreads();
    #pragma unroll
    for (int i = 0; i < 16; ++i) {
        int d = i * 4 + ty;
        Vt[((size_t)kvh * HD + d) * SEQ + s0 + tx] = __float2bfloat16(tile[tx][d]);
    }
}

// ---------------- MFMA flash attention: 4 waves x 16-row strips, KVBLK=64 ----------------
__global__ __launch_bounds__(256) void attn_mfma_kernel(const bf16* __restrict__ Qh,
                                                        const bf16* __restrict__ Kh,
                                                        const bf16* __restrict__ Vt,
                                                        bf16* __restrict__ o) {
    __shared__ char lds[32768];
    char* Qs = lds;
    char* Ks = lds + 8192;
    char* Vs = lds + 16384;
    char* Ps = lds + 24576;
    const int t = threadIdx.x, lane = t & 63, w = t >> 6;
    const int g = lane >> 4, lo = lane & 15;
    const int h = blockIdx.y, kvh = h >> 2;
    const int qbase = blockIdx.x * 64;
    const int strip = w * 16;
    const bf16* qsrc = Qh + ((size_t)h * SEQ + qbase) * HD;
    const bf16* ksrc = Kh + (size_t)kvh * SEQ * HD;
    const bf16* vsrc = Vt + (size_t)kvh * HD * SEQ;

    #pragma unroll
    for (int c = t; c < 512; c += 256) {
        int row = c >> 3, col = c & 7;
        *(s8v*)(Qs + row * 128 + ((col * 16) ^ ((row & 7) << 4))) =
            *(const s8v*)(qsrc + row * HD + col * 8);
    }

    f32x4 oacc[4];
    f32x4 z = {0.f, 0.f, 0.f, 0.f};
    #pragma unroll
    for (int dj = 0; dj < 4; ++dj) oacc[dj] = z;
    float m0[4], lsum[4];
    #pragma unroll
    for (int r = 0; r < 4; ++r) { m0[r] = -INFINITY; lsum[r] = 0.f; }

    const int qt = blockIdx.x;
    for (int kt = 0; kt <= qt; ++kt) {
        __syncthreads();
        const bf16* kq = ksrc + (size_t)(kt * 64) * HD;
        const bf16* vq = vsrc + kt * 64;
        #pragma unroll
        for (int c = t; c < 512; c += 256) {
            int row = c >> 3, col = c & 7;
            int swz = (col * 16) ^ ((row & 7) << 4);
            *(s8v*)(Ks + row * 128 + swz) = *(const s8v*)(kq + row * HD + col * 8);
            *(s8v*)(Vs + row * 128 + swz) = *(const s8v*)(vq + (size_t)row * SEQ + col * 8);
        }
        __syncthreads();

        s8v qa0 = *(const s8v*)(Qs + (strip + lo) * 128 + ((g * 16) ^ ((lo & 7) << 4)));
        s8v qa1 = *(const s8v*)(Qs + (strip + lo) * 128 + ((64 + g * 16) ^ ((lo & 7) << 4)));
        f32x4 sacc[4];
        #pragma unroll
        for (int j = 0; j < 4; ++j) {
            s8v kb0 = *(const s8v*)(Ks + (j * 16 + lo) * 128 + ((g * 16) ^ ((lo & 7) << 4)));
            s8v kb1 = *(const s8v*)(Ks + (j * 16 + lo) * 128 + ((64 + g * 16) ^ ((lo & 7) << 4)));
            f32x4 sv = __builtin_amdgcn_mfma_f32_16x16x32_bf16(qa0, kb0, z, 0, 0, 0);
            sacc[j] = __builtin_amdgcn_mfma_f32_16x16x32_bf16(qa1, kb1, sv, 0, 0, 0);
        }
        #pragma unroll
        for (int j = 0; j < 4; ++j) {
            int kgl = kt * 64 + j * 16 + lo;
            #pragma unroll
            for (int r = 0; r < 4; ++r) {
                int qgl = qbase + strip + g * 4 + r;
                float sv = sacc[j][r] * 0.125f;
                sacc[j][r] = (kgl <= qgl) ? sv : -INFINITY;
            }
        }
        float rmax[4], resc[4];
        #pragma unroll
        for (int r = 0; r < 4; ++r) {
            float mx = fmaxf(fmaxf(sacc[0][r], sacc[1][r]), fmaxf(sacc[2][r], sacc[3][r]));
            mx = fmaxf(mx, __shfl_xor(mx, 1, 64));
            mx = fmaxf(mx, __shfl_xor(mx, 2, 64));
            mx = fmaxf(mx, __shfl_xor(mx, 4, 64));
            mx = fmaxf(mx, __shfl_xor(mx, 8, 64));
            float mn = fmaxf(m0[r], mx);
            resc[r] = expf(m0[r] - mn);
            m0[r] = mn;
            rmax[r] = mn;
        }
        #pragma unroll
        for (int j = 0; j < 4; ++j)
            #pragma unroll
            for (int r = 0; r < 4; ++r)
                sacc[j][r] = expf(sacc[j][r] - rmax[r]);
        #pragma unroll
        for (int r = 0; r < 4; ++r) {
            float ps = sacc[0][r] + sacc[1][r] + sacc[2][r] + sacc[3][r];
            lsum[r] = lsum[r] * resc[r] + ps;
        }
        #pragma unroll
        for (int dj = 0; dj < 4; ++dj)
            #pragma unroll
            for (int r = 0; r < 4; ++r)
                oacc[dj][r] *= resc[r];
        #pragma unroll
        for (int j = 0; j < 4; ++j) {
            #pragma unroll
            for (int r = 0; r < 4; ++r) {
                int prow = strip + g * 4 + r;
                int pcol = j * 16 + lo;
                *(bf16*)(Ps + prow * 128 + ((pcol * 2) ^ ((prow & 7) << 4))) =
                    __float2bfloat16(sacc[j][r]);
            }
        }
        s8v pa0 = *(const s8v*)(Ps + (strip + lo) * 128 + ((g * 16) ^ ((lo & 7) << 4)));
        s8v pa1 = *(const s8v*)(Ps + (strip + lo) * 128 + ((64 + g * 16) ^ ((lo & 7) << 4)));
        #pragma unroll
        for (int dj = 0; dj < 4; ++dj) {
            s8v vb0 = *(const s8v*)(Vs + (dj * 16 + lo) * 128 + ((g * 16) ^ ((lo & 7) << 4)));
            s8v vb1 = *(const s8v*)(Vs + (dj * 16 + lo) * 128 + ((64 + g * 16) ^ ((lo & 7) << 4)));
            oacc[dj] = __builtin_amdgcn_mfma_f32_16x16x32_bf16(pa0, vb0, oacc[dj], 0, 0, 0);
            oacc[dj] = __builtin_amdgcn_mfma_f32_16x16x32_bf16(pa1, vb1, oacc[dj], 0, 0, 0);
        }
    }
    float invl[4];
    #pragma unroll
    for (int r = 0; r < 4; ++r) {
        float l = lsum[r];
        l += __shfl_xor(l, 1, 64);
        l += __shfl_xor(l, 2, 64);
        l += __shfl_xor(l, 4, 64);
        l += __shfl_xor(l, 8, 64);
        invl[r] = 1.f / l;
    }
    #pragma unroll
    for (int dj = 0; dj < 4; ++dj) {
        #pragma unroll
        for (int r = 0; r < 4; ++r) {
            int qrow = qbase + strip + g * 4 + r;
            o[(size_t)qrow * DM + h * HD + dj * 16 + lo] =
                __float2bfloat16(oacc[dj][r] * invl[r]);
        }
    }
}

// ---------------- silu(gate)*up from fused bf16 gu buffer -> bf16 ----------------
__global__ __launch_bounds__(256) void silu_mul_kernel(const bf16* __restrict__ gu,
                                                       bf16* __restrict__ ga) {
    int i = blockIdx.x * 256 + threadIdx.x;   // SEQ*FF/8 threads
    int s = i >> 10;                           // FF/8 = 1024 groups per row
    int c8 = i & 1023;
    union { s8v v; bf16 h[8]; } gv, uv, ov;
    gv.v = *(const s8v*)(gu + (size_t)s * (2 * FF) + c8 * 8);
    uv.v = *(const s8v*)(gu + (size_t)s * (2 * FF) + FF + c8 * 8);
    #pragma unroll
    for (int j = 0; j < 8; ++j) {
        float g = __bfloat162float(gv.h[j]);
        float u = __bfloat162float(uv.h[j]);
        ov.h[j] = __float2bfloat16(g / (1.f + expf(-g)) * u);
    }
    *(s8v*)(ga + (size_t)s * FF + c8 * 8) = ov.v;
}

extern "C" void kernel_launch(void* const* d_in, const int* in_sizes, int n_in,
                              void* d_out, int out_size, void* d_ws, size_t ws_size,
                              hipStream_t stream) {
    const int*   ids   = (const int*)d_in[0];
    const float* emb   = (const float*)d_in[1];
    const float* wq    = (const float*)d_in[2];
    const float* wk    = (const float*)d_in[3];
    const float* wv    = (const float*)d_in[4];
    const float* wo    = (const float*)d_in[5];
    const float* wgate = (const float*)d_in[6];
    const float* wup   = (const float*)d_in[7];
    const float* wdown = (const float*)d_in[8];
    const float* ln1   = (const float*)d_in[9];
    const float* ln2   = (const float*)d_in[10];
    float* x = (float*)d_out;

    const size_t QKV_W = (size_t)QKVW * DM;
    const size_t O_W   = (size_t)DM * DM;
    const size_t GU_W  = (size_t)2 * FF * DM;
    const size_t D_W   = (size_t)DM * FF;

    bf16* wqkvT = (bf16*)d_ws;
    bf16* woT   = wqkvT + 2 * QKV_W;
    bf16* wguT  = woT   + 2 * O_W;
    bf16* wdT   = wguT  + 2 * GU_W;
    bf16* h_bf  = wdT   + 2 * D_W;
    bf16* attnb = h_bf  + (size_t)SEQ * DM;
    bf16* gub   = attnb + (size_t)SEQ * DM;         // bf16 gate|up, SEQ x 2FF
    bf16* gab   = gub   + (size_t)SEQ * 2 * FF;
    bf16* Qhb   = gab   + (size_t)SEQ * FF;
    bf16* Khb   = Qhb   + (size_t)NH * SEQ * HD;
    bf16* Vtb   = Khb   + (size_t)NKVH * SEQ * HD;
    float* qkv  = (float*)(Vtb + (size_t)NKVH * HD * SEQ);
    float* psum = qkv + (size_t)SEQ * QKVW;          // 4 x SEQ x DM f32 partials

    auto T = [&](const float* src, bf16* dst, int K_, int N_) {
        transpose_bf16_kernel<<<dim3(N_ / 64, K_ / 64), 256, 0, stream>>>(src, dst, K_, N_);
    };

    for (int l = 0; l < NL; ++l) {
        T(wq + (size_t)l * DM * DM,        wqkvT + l * QKV_W,                 DM, DM);
        T(wk + (size_t)l * DM * 512,       wqkvT + l * QKV_W + (size_t)DM * DM,   DM, 512);
        T(wv + (size_t)l * DM * 512,       wqkvT + l * QKV_W + (size_t)2560 * DM, DM, 512);
        T(wo + (size_t)l * DM * DM,        woT + l * O_W,                     DM, DM);
        T(wgate + (size_t)l * DM * FF,     wguT + l * GU_W,                   DM, FF);
        T(wup + (size_t)l * DM * FF,       wguT + l * GU_W + (size_t)FF * DM, DM, FF);
        T(wdown + (size_t)l * FF * DM,     wdT + l * D_W,                     FF, DM);
    }

    embed_kernel<<<SEQ, 256, 0, stream>>>(ids, emb, x);

    for (int l = 0; l < NL; ++l) {
        rms_kernel<<<SEQ, 256, 0, stream>>>(x, ln1 + (size_t)l * DM, h_bf);

        // qkv: M=1024, N=3072, K=2048 -> f32 out (grid 24x8)
        mfma_gemm_kernel<false><<<dim3(QKVW / 128, SEQ / 128, 1), 256, 0, stream>>>(
            h_bf, wqkvT + l * QKV_W, qkv, nullptr, SEQ, QKVW, DM, DM, 0);

        rope_qk_kernel<<<(SEQ * (NH + NKVH) * 32) / 256, 256, 0, stream>>>(qkv, Qhb, Khb);
        vtrans_kernel<<<dim3(SEQ / 64, NKVH), 256, 0, stream>>>(qkv, Vtb);

        attn_mfma_kernel<<<dim3(SEQ / 64, NH), 256, 0, stream>>>(Qhb, Khb, Vtb, attnb);

        // wo: M=1024, N=2048, K=2048, split-K x4 -> psum; x += sum(psum)
        mfma_gemm_kernel<false><<<dim3(DM / 128, SEQ / 128, 4), 256, 0, stream>>>(
            attnb, woT + l * O_W, psum, nullptr, SEQ, DM, DM, DM / 4, 0);
        reduce4_kernel<<<(SEQ * DM / 4) / 256, 256, 0, stream>>>(x, psum);

        rms_kernel<<<SEQ, 256, 0, stream>>>(x, ln2 + (size_t)l * DM, h_bf);

        // gate|up: M=1024, N=16384, K=2048 -> bf16 out (grid 128x8)
        mfma_gemm_kernel<true><<<dim3((2 * FF) / 128, SEQ / 128, 1), 256, 0, stream>>>(
            h_bf, wguT + l * GU_W, nullptr, gub, SEQ, 2 * FF, DM, DM, 0);

        silu_mul_kernel<<<(SEQ * FF / 8) / 256, 256, 0, stream>>>(gub, gab);

        // down: M=1024, N=2048, K=8192, split-K x4 -> psum; x += sum(psum)
        mfma_gemm_kernel<false><<<dim3(DM / 128, SEQ / 128, 4), 256, 0, stream>>>(
            gab, wdT + l * D_W, psum, nullptr, SEQ, DM, FF, FF / 4, 0);
        reduce4_kernel<<<(SEQ * DM / 4) / 256, 256, 0, stream>>>(x, psum);
    }
}

// Round 6
// 648.701 us; speedup vs baseline: 7.8147x; 1.2545x over previous
//
#include <hip/hip_runtime.h>
#include <hip/hip_bf16.h>
#include <math.h>

#define NL 2
#define NH 32
#define NKVH 8
#define HD 64
#define DM 2048
#define FF 8192
#define SEQ 1024
#define QKVW 3072
#define RMS_EPS 1e-5f

typedef short s8v __attribute__((ext_vector_type(8)));
typedef short s4v __attribute__((ext_vector_type(4)));
typedef float f32x4 __attribute__((ext_vector_type(4)));
typedef __hip_bfloat16 bf16;

// ---------------- embed gather ----------------
__global__ __launch_bounds__(256) void embed_kernel(const int* __restrict__ ids,
                                                    const float* __restrict__ emb,
                                                    float* __restrict__ x) {
    int s = blockIdx.x;
    int row = ids[s];
    const float4* src = (const float4*)(emb + (size_t)row * DM);
    float4* dst = (float4*)(x + (size_t)s * DM);
    #pragma unroll
    for (int i = 0; i < 2; ++i)
        dst[threadIdx.x + i * 256] = src[threadIdx.x + i * 256];
}

// ---------------- RMSNorm: f32 in, bf16 out ----------------
__global__ __launch_bounds__(256) void rms_kernel(const float* __restrict__ x,
                                                  const float* __restrict__ g,
                                                  bf16* __restrict__ out) {
    int s = blockIdx.x;
    const float4* row = (const float4*)(x + (size_t)s * DM);
    float4 v0 = row[threadIdx.x * 2];
    float4 v1 = row[threadIdx.x * 2 + 1];
    float ss = v0.x*v0.x + v0.y*v0.y + v0.z*v0.z + v0.w*v0.w
             + v1.x*v1.x + v1.y*v1.y + v1.z*v1.z + v1.w*v1.w;
    #pragma unroll
    for (int o = 32; o > 0; o >>= 1) ss += __shfl_down(ss, o, 64);
    __shared__ float red[4];
    if ((threadIdx.x & 63) == 0) red[threadIdx.x >> 6] = ss;
    __syncthreads();
    float total = red[0] + red[1] + red[2] + red[3];
    float inv = 1.0f / sqrtf(total / (float)DM + RMS_EPS);
    const float4* g4 = (const float4*)g;
    float4 ga = g4[threadIdx.x * 2], gb = g4[threadIdx.x * 2 + 1];
    union { bf16 h[8]; s8v v; } u;
    u.h[0] = __float2bfloat16(v0.x * inv * ga.x);
    u.h[1] = __float2bfloat16(v0.y * inv * ga.y);
    u.h[2] = __float2bfloat16(v0.z * inv * ga.z);
    u.h[3] = __float2bfloat16(v0.w * inv * ga.w);
    u.h[4] = __float2bfloat16(v1.x * inv * gb.x);
    u.h[5] = __float2bfloat16(v1.y * inv * gb.y);
    u.h[6] = __float2bfloat16(v1.z * inv * gb.z);
    u.h[7] = __float2bfloat16(v1.w * inv * gb.w);
    *(s8v*)(out + (size_t)s * DM + threadIdx.x * 8) = u.v;
}

// ---------------- bf16 MFMA GEMM with in-kernel f32-weight transpose ----------------
// C[M,N] = A[M,Ka-slice] @ W[K][N]  (W read directly as f32, k-strided, cvt+swizzled to LDS)
// N can be a concatenation of up to 3 sources: Wa (Na cols) | Wb (Nb cols) | Wc (rest).
// BM=BN=128, BK=64, 256 threads, 4 waves. blockIdx.z = split-K chunk.
template<bool OUTBF>
__global__ __launch_bounds__(256) void gemm_f32w_kernel(const bf16* __restrict__ A, int Ka,
                                                        const float* __restrict__ Wa, int Na,
                                                        const float* __restrict__ Wb, int Nb,
                                                        const float* __restrict__ Wc,
                                                        float* __restrict__ C,
                                                        bf16* __restrict__ Cb,
                                                        int M, int N, int Kchunk) {
    __shared__ bf16 As[2][128 * 64];
    __shared__ bf16 Bs[2][128 * 64];
    const int t = threadIdx.x, lane = t & 63;
    const int w = t >> 6;
    const int m0 = blockIdx.y * 128, n0 = blockIdx.x * 128;
    const size_t koff = (size_t)blockIdx.z * Kchunk;

    // ---- B staging map: thread owns column nl, k-octets kob+2u ----
    const int nl = t & 127;
    const int kob = t >> 7;                 // 0 or 1
    const int ng = n0 + nl;
    const float* wp; int wstr;
    if (ng < Na)           { wp = Wa + ng;             wstr = Na; }
    else if (ng < Na + Nb) { wp = Wb + (ng - Na);      wstr = Nb; }
    else                   { wp = Wc + (ng - Na - Nb); wstr = N - Na - Nb; }
    wp += koff * (size_t)wstr;

    // ---- A staging map: thread owns row am(+32u), k-octet ako ----
    const int ako = t & 7, am = t >> 3;
    const bf16* apt = A + (size_t)(m0 + am) * Ka + koff + ako * 8;

    const int wm = (w >> 1) * 64, wn = (w & 1) * 64;
    const int fr = lane & 15, sl = lane >> 4;

    f32x4 acc[4][4];
    f32x4 z = {0.f, 0.f, 0.f, 0.f};
    #pragma unroll
    for (int i = 0; i < 4; ++i)
        #pragma unroll
        for (int j = 0; j < 4; ++j) acc[i][j] = z;

    float rb[4][8];
    s8v ra[4];

    auto LOADR = [&](int tile) {
        const int k0 = tile * 64;
        #pragma unroll
        for (int u = 0; u < 4; ++u) {
            const float* p = wp + (size_t)(k0 + (kob + 2 * u) * 8) * wstr;
            #pragma unroll
            for (int j = 0; j < 8; ++j) rb[u][j] = p[(size_t)j * wstr];
            ra[u] = *(const s8v*)(apt + (size_t)(32 * u) * Ka + k0);
        }
    };
    auto WRITE = [&](bf16* AsB, bf16* BsB) {
        #pragma unroll
        for (int u = 0; u < 4; ++u) {
            union { bf16 h[8]; s8v v; } cv;
            #pragma unroll
            for (int j = 0; j < 8; ++j) cv.h[j] = __float2bfloat16(rb[u][j]);
            int ko = kob + 2 * u;
            *(s8v*)((char*)BsB + nl * 128 + ((ko * 16) ^ ((nl & 7) << 4))) = cv.v;
            int m = am + 32 * u;
            *(s8v*)((char*)AsB + m * 128 + ((ako * 16) ^ ((m & 7) << 4))) = ra[u];
        }
    };
    auto COMPUTE = [&](const bf16* AsB, const bf16* BsB) {
        #pragma unroll
        for (int kk = 0; kk < 2; ++kk) {
            const int kb = kk * 64 + sl * 16;
            s8v af[4], bfv[4];
            #pragma unroll
            for (int i = 0; i < 4; ++i) {
                int m = wm + i * 16 + fr;
                af[i] = *(const s8v*)((const char*)AsB + m * 128 + (kb ^ ((m & 7) << 4)));
            }
            #pragma unroll
            for (int j = 0; j < 4; ++j) {
                int n = wn + j * 16 + fr;
                bfv[j] = *(const s8v*)((const char*)BsB + n * 128 + (kb ^ ((n & 7) << 4)));
            }
            #pragma unroll
            for (int i = 0; i < 4; ++i)
                #pragma unroll
                for (int j = 0; j < 4; ++j)
                    acc[i][j] = __builtin_amdgcn_mfma_f32_16x16x32_bf16(af[i], bfv[j], acc[i][j], 0, 0, 0);
        }
    };

    const int nt = Kchunk / 64;
    LOADR(0);
    WRITE(&As[0][0], &Bs[0][0]);   // compiler inserts vmcnt before first reg use
    __syncthreads();
    for (int tt = 0; tt < nt; ++tt) {
        const int cur = tt & 1;
        if (tt + 1 < nt) LOADR(tt + 1);          // regs free; loads fly under MFMA
        COMPUTE(&As[cur][0], &Bs[cur][0]);
        if (tt + 1 < nt) {
            __syncthreads();                     // all waves done reading buf cur^1
            WRITE(&As[cur ^ 1][0], &Bs[cur ^ 1][0]);
            __syncthreads();                     // writes visible
        }
    }

    float* Cz = C + (size_t)blockIdx.z * M * N;
    #pragma unroll
    for (int i = 0; i < 4; ++i) {
        #pragma unroll
        for (int j = 0; j < 4; ++j) {
            #pragma unroll
            for (int q = 0; q < 4; ++q) {
                int row = m0 + wm + i * 16 + sl * 4 + q;
                int col = n0 + wn + j * 16 + fr;
                float vv = acc[i][j][q];
                if constexpr (OUTBF) Cb[(size_t)row * N + col] = __float2bfloat16(vv);
                else                 Cz[(size_t)row * N + col] = vv;
            }
        }
    }
}

// ---------------- split-K reduce: x += p0+p1+p2+p3 ----------------
__global__ __launch_bounds__(256) void reduce4_kernel(float* __restrict__ x,
                                                      const float* __restrict__ p) {
    const int n4 = SEQ * DM / 4;
    int i = blockIdx.x * 256 + threadIdx.x;
    if (i >= n4) return;
    float4 a = ((const float4*)x)[i];
    #pragma unroll
    for (int c = 0; c < 4; ++c) {
        float4 v = ((const float4*)p)[i + c * n4];
        a.x += v.x; a.y += v.y; a.z += v.z; a.w += v.w;
    }
    ((float4*)x)[i] = a;
}

// ---------------- RoPE: f32 qkv -> bf16 Qh[h][s][d], Kh[kvh][s][d] ----------------
__global__ __launch_bounds__(256) void rope_qk_kernel(const float* __restrict__ qkv,
                                                      bf16* __restrict__ Qh,
                                                      bf16* __restrict__ Kh) {
    int idx = blockIdx.x * 256 + threadIdx.x;
    int i = idx & 31;
    int hh = (idx >> 5) % (NH + NKVH);
    int s = idx / (32 * (NH + NKVH));
    bool isq = hh < NH;
    int col = isq ? hh * HD + i : DM + (hh - NH) * HD + i;
    float a = qkv[(size_t)s * QKVW + col];
    float b = qkv[(size_t)s * QKVW + col + 32];
    float inv = exp2f(-(float)i * 0.41524101186092029f);
    float ang = (float)s * inv;
    float c = cosf(ang), sn = sinf(ang);
    float ra = a * c - b * sn;
    float rb = b * c + a * sn;
    if (isq) {
        bf16* p = Qh + ((size_t)hh * SEQ + s) * HD + i;
        p[0]  = __float2bfloat16(ra);
        p[32] = __float2bfloat16(rb);
    } else {
        bf16* p = Kh + ((size_t)(hh - NH) * SEQ + s) * HD + i;
        p[0]  = __float2bfloat16(ra);
        p[32] = __float2bfloat16(rb);
    }
}

// ---------------- V transpose: f32 qkv -> bf16 Vt[kvh][d][s] ----------------
__global__ __launch_bounds__(256) void vtrans_kernel(const float* __restrict__ qkv,
                                                     bf16* __restrict__ Vt) {
    __shared__ float tile[64][65];
    const int s0 = blockIdx.x * 64;
    const int kvh = blockIdx.y;
    const int tx = threadIdx.x & 63, ty = threadIdx.x >> 6;
    #pragma unroll
    for (int i = 0; i < 16; ++i)
        tile[i * 4 + ty][tx] = qkv[(size_t)(s0 + i * 4 + ty) * QKVW + DM + 512 + kvh * HD + tx];
    __syncthreads();
    #pragma unroll
    for (int i = 0; i < 16; ++i) {
        int d = i * 4 + ty;
        Vt[((size_t)kvh * HD + d) * SEQ + s0 + tx] = __float2bfloat16(tile[tx][d]);
    }
}

// ---------------- MFMA flash attention: 4 waves x 16-row strips, KVBLK=64 ----------------
__global__ __launch_bounds__(256) void attn_mfma_kernel(const bf16* __restrict__ Qh,
                                                        const bf16* __restrict__ Kh,
                                                        const bf16* __restrict__ Vt,
                                                        bf16* __restrict__ o) {
    __shared__ char lds[32768];
    char* Qs = lds;
    char* Ks = lds + 8192;
    char* Vs = lds + 16384;
    char* Ps = lds + 24576;
    const int t = threadIdx.x, lane = t & 63, w = t >> 6;
    const int g = lane >> 4, lo = lane & 15;
    const int h = blockIdx.y, kvh = h >> 2;
    const int qbase = blockIdx.x * 64;
    const int strip = w * 16;
    const bf16* qsrc = Qh + ((size_t)h * SEQ + qbase) * HD;
    const bf16* ksrc = Kh + (size_t)kvh * SEQ * HD;
    const bf16* vsrc = Vt + (size_t)kvh * HD * SEQ;

    #pragma unroll
    for (int c = t; c < 512; c += 256) {
        int row = c >> 3, col = c & 7;
        *(s8v*)(Qs + row * 128 + ((col * 16) ^ ((row & 7) << 4))) =
            *(const s8v*)(qsrc + row * HD + col * 8);
    }

    f32x4 oacc[4];
    f32x4 z = {0.f, 0.f, 0.f, 0.f};
    #pragma unroll
    for (int dj = 0; dj < 4; ++dj) oacc[dj] = z;
    float m0[4], lsum[4];
    #pragma unroll
    for (int r = 0; r < 4; ++r) { m0[r] = -INFINITY; lsum[r] = 0.f; }

    const int qt = blockIdx.x;
    for (int kt = 0; kt <= qt; ++kt) {
        __syncthreads();
        const bf16* kq = ksrc + (size_t)(kt * 64) * HD;
        const bf16* vq = vsrc + kt * 64;
        #pragma unroll
        for (int c = t; c < 512; c += 256) {
            int row = c >> 3, col = c & 7;
            int swz = (col * 16) ^ ((row & 7) << 4);
            *(s8v*)(Ks + row * 128 + swz) = *(const s8v*)(kq + row * HD + col * 8);
            *(s8v*)(Vs + row * 128 + swz) = *(const s8v*)(vq + (size_t)row * SEQ + col * 8);
        }
        __syncthreads();

        s8v qa0 = *(const s8v*)(Qs + (strip + lo) * 128 + ((g * 16) ^ ((lo & 7) << 4)));
        s8v qa1 = *(const s8v*)(Qs + (strip + lo) * 128 + ((64 + g * 16) ^ ((lo & 7) << 4)));
        f32x4 sacc[4];
        #pragma unroll
        for (int j = 0; j < 4; ++j) {
            s8v kb0 = *(const s8v*)(Ks + (j * 16 + lo) * 128 + ((g * 16) ^ ((lo & 7) << 4)));
            s8v kb1 = *(const s8v*)(Ks + (j * 16 + lo) * 128 + ((64 + g * 16) ^ ((lo & 7) << 4)));
            f32x4 sv = __builtin_amdgcn_mfma_f32_16x16x32_bf16(qa0, kb0, z, 0, 0, 0);
            sacc[j] = __builtin_amdgcn_mfma_f32_16x16x32_bf16(qa1, kb1, sv, 0, 0, 0);
        }
        #pragma unroll
        for (int j = 0; j < 4; ++j) {
            int kgl = kt * 64 + j * 16 + lo;
            #pragma unroll
            for (int r = 0; r < 4; ++r) {
                int qgl = qbase + strip + g * 4 + r;
                float sv = sacc[j][r] * 0.125f;
                sacc[j][r] = (kgl <= qgl) ? sv : -INFINITY;
            }
        }
        float rmax[4], resc[4];
        #pragma unroll
        for (int r = 0; r < 4; ++r) {
            float mx = fmaxf(fmaxf(sacc[0][r], sacc[1][r]), fmaxf(sacc[2][r], sacc[3][r]));
            mx = fmaxf(mx, __shfl_xor(mx, 1, 64));
            mx = fmaxf(mx, __shfl_xor(mx, 2, 64));
            mx = fmaxf(mx, __shfl_xor(mx, 4, 64));
            mx = fmaxf(mx, __shfl_xor(mx, 8, 64));
            float mn = fmaxf(m0[r], mx);
            resc[r] = expf(m0[r] - mn);
            m0[r] = mn;
            rmax[r] = mn;
        }
        #pragma unroll
        for (int j = 0; j < 4; ++j)
            #pragma unroll
            for (int r = 0; r < 4; ++r)
                sacc[j][r] = expf(sacc[j][r] - rmax[r]);
        #pragma unroll
        for (int r = 0; r < 4; ++r) {
            float ps = sacc[0][r] + sacc[1][r] + sacc[2][r] + sacc[3][r];
            lsum[r] = lsum[r] * resc[r] + ps;
        }
        #pragma unroll
        for (int dj = 0; dj < 4; ++dj)
            #pragma unroll
            for (int r = 0; r < 4; ++r)
                oacc[dj][r] *= resc[r];
        #pragma unroll
        for (int j = 0; j < 4; ++j) {
            #pragma unroll
            for (int r = 0; r < 4; ++r) {
                int prow = strip + g * 4 + r;
                int pcol = j * 16 + lo;
                *(bf16*)(Ps + prow * 128 + ((pcol * 2) ^ ((prow & 7) << 4))) =
                    __float2bfloat16(sacc[j][r]);
            }
        }
        s8v pa0 = *(const s8v*)(Ps + (strip + lo) * 128 + ((g * 16) ^ ((lo & 7) << 4)));
        s8v pa1 = *(const s8v*)(Ps + (strip + lo) * 128 + ((64 + g * 16) ^ ((lo & 7) << 4)));
        #pragma unroll
        for (int dj = 0; dj < 4; ++dj) {
            s8v vb0 = *(const s8v*)(Vs + (dj * 16 + lo) * 128 + ((g * 16) ^ ((lo & 7) << 4)));
            s8v vb1 = *(const s8v*)(Vs + (dj * 16 + lo) * 128 + ((64 + g * 16) ^ ((lo & 7) << 4)));
            oacc[dj] = __builtin_amdgcn_mfma_f32_16x16x32_bf16(pa0, vb0, oacc[dj], 0, 0, 0);
            oacc[dj] = __builtin_amdgcn_mfma_f32_16x16x32_bf16(pa1, vb1, oacc[dj], 0, 0, 0);
        }
    }
    float invl[4];
    #pragma unroll
    for (int r = 0; r < 4; ++r) {
        float l = lsum[r];
        l += __shfl_xor(l, 1, 64);
        l += __shfl_xor(l, 2, 64);
        l += __shfl_xor(l, 4, 64);
        l += __shfl_xor(l, 8, 64);
        invl[r] = 1.f / l;
    }
    #pragma unroll
    for (int dj = 0; dj < 4; ++dj) {
        #pragma unroll
        for (int r = 0; r < 4; ++r) {
            int qrow = qbase + strip + g * 4 + r;
            o[(size_t)qrow * DM + h * HD + dj * 16 + lo] =
                __float2bfloat16(oacc[dj][r] * invl[r]);
        }
    }
}

// ---------------- silu(gate)*up from fused bf16 gu buffer -> bf16 ----------------
__global__ __launch_bounds__(256) void silu_mul_kernel(const bf16* __restrict__ gu,
                                                       bf16* __restrict__ ga) {
    int i = blockIdx.x * 256 + threadIdx.x;
    int s = i >> 10;
    int c8 = i & 1023;
    union { s8v v; bf16 h[8]; } gv, uv, ov;
    gv.v = *(const s8v*)(gu + (size_t)s * (2 * FF) + c8 * 8);
    uv.v = *(const s8v*)(gu + (size_t)s * (2 * FF) + FF + c8 * 8);
    #pragma unroll
    for (int j = 0; j < 8; ++j) {
        float g = __bfloat162float(gv.h[j]);
        float u = __bfloat162float(uv.h[j]);
        ov.h[j] = __float2bfloat16(g / (1.f + expf(-g)) * u);
    }
    *(s8v*)(ga + (size_t)s * FF + c8 * 8) = ov.v;
}

extern "C" void kernel_launch(void* const* d_in, const int* in_sizes, int n_in,
                              void* d_out, int out_size, void* d_ws, size_t ws_size,
                              hipStream_t stream) {
    const int*   ids   = (const int*)d_in[0];
    const float* emb   = (const float*)d_in[1];
    const float* wq    = (const float*)d_in[2];
    const float* wk    = (const float*)d_in[3];
    const float* wv    = (const float*)d_in[4];
    const float* wo    = (const float*)d_in[5];
    const float* wgate = (const float*)d_in[6];
    const float* wup   = (const float*)d_in[7];
    const float* wdown = (const float*)d_in[8];
    const float* ln1   = (const float*)d_in[9];
    const float* ln2   = (const float*)d_in[10];
    float* x = (float*)d_out;

    bf16* h_bf  = (bf16*)d_ws;
    bf16* attnb = h_bf  + (size_t)SEQ * DM;
    bf16* gub   = attnb + (size_t)SEQ * DM;
    bf16* gab   = gub   + (size_t)SEQ * 2 * FF;
    bf16* Qhb   = gab   + (size_t)SEQ * FF;
    bf16* Khb   = Qhb   + (size_t)NH * SEQ * HD;
    bf16* Vtb   = Khb   + (size_t)NKVH * SEQ * HD;
    float* qkv  = (float*)(Vtb + (size_t)NKVH * HD * SEQ);
    float* psum = qkv + (size_t)SEQ * QKVW;

    embed_kernel<<<SEQ, 256, 0, stream>>>(ids, emb, x);

    for (int l = 0; l < NL; ++l) {
        const float* wq_l = wq + (size_t)l * DM * DM;
        const float* wk_l = wk + (size_t)l * DM * 512;
        const float* wv_l = wv + (size_t)l * DM * 512;
        const float* wo_l = wo + (size_t)l * DM * DM;
        const float* wg_l = wgate + (size_t)l * DM * FF;
        const float* wu_l = wup   + (size_t)l * DM * FF;
        const float* wd_l = wdown + (size_t)l * FF * DM;

        rms_kernel<<<SEQ, 256, 0, stream>>>(x, ln1 + (size_t)l * DM, h_bf);

        // qkv: fused wq|wk|wv, M=1024 N=3072 K=2048 -> f32
        gemm_f32w_kernel<false><<<dim3(QKVW / 128, SEQ / 128, 1), 256, 0, stream>>>(
            h_bf, DM, wq_l, DM, wk_l, 512, wv_l, qkv, nullptr, SEQ, QKVW, DM);

        rope_qk_kernel<<<(SEQ * (NH + NKVH) * 32) / 256, 256, 0, stream>>>(qkv, Qhb, Khb);
        vtrans_kernel<<<dim3(SEQ / 64, NKVH), 256, 0, stream>>>(qkv, Vtb);

        attn_mfma_kernel<<<dim3(SEQ / 64, NH), 256, 0, stream>>>(Qhb, Khb, Vtb, attnb);

        // wo: M=1024 N=2048 K=2048, split-K x4 -> psum; x += sum(psum)
        gemm_f32w_kernel<false><<<dim3(DM / 128, SEQ / 128, 4), 256, 0, stream>>>(
            attnb, DM, wo_l, DM, nullptr, 0, nullptr, psum, nullptr, SEQ, DM, DM / 4);
        reduce4_kernel<<<(SEQ * DM / 4) / 256, 256, 0, stream>>>(x, psum);

        rms_kernel<<<SEQ, 256, 0, stream>>>(x, ln2 + (size_t)l * DM, h_bf);

        // gate|up: fused wgate|wup, M=1024 N=16384 K=2048 -> bf16
        gemm_f32w_kernel<true><<<dim3((2 * FF) / 128, SEQ / 128, 1), 256, 0, stream>>>(
            h_bf, DM, wg_l, FF, wu_l, FF, nullptr, nullptr, gub, SEQ, 2 * FF, DM);

        silu_mul_kernel<<<(SEQ * FF / 8) / 256, 256, 0, stream>>>(gub, gab);

        // down: M=1024 N=2048 K=8192, split-K x4 -> psum; x += sum(psum)
        gemm_f32w_kernel<false><<<dim3(DM / 128, SEQ / 128, 4), 256, 0, stream>>>(
            gab, FF, wd_l, DM, nullptr, 0, nullptr, psum, nullptr, SEQ, DM, FF / 4);
        reduce4_kernel<<<(SEQ * DM / 4) / 256, 256, 0, stream>>>(x, psum);
    }
}

// Round 7
// 624.226 us; speedup vs baseline: 8.1210x; 1.0392x over previous
//
#include <hip/hip_runtime.h>
#include <hip/hip_bf16.h>
#include <math.h>

#define NL 2
#define NH 32
#define NKVH 8
#define HD 64
#define DM 2048
#define FF 8192
#define SEQ 1024
#define QKVW 3072
#define RMS_EPS 1e-5f

typedef short s8v __attribute__((ext_vector_type(8)));
typedef short s4v __attribute__((ext_vector_type(4)));
typedef float f32x4 __attribute__((ext_vector_type(4)));
typedef __hip_bfloat16 bf16;

// ---------------- embed gather ----------------
__global__ __launch_bounds__(256) void embed_kernel(const int* __restrict__ ids,
                                                    const float* __restrict__ emb,
                                                    float* __restrict__ x) {
    int s = blockIdx.x;
    int row = ids[s];
    const float4* src = (const float4*)(emb + (size_t)row * DM);
    float4* dst = (float4*)(x + (size_t)s * DM);
    #pragma unroll
    for (int i = 0; i < 2; ++i)
        dst[threadIdx.x + i * 256] = src[threadIdx.x + i * 256];
}

// ---------------- RMSNorm: f32 in, bf16 out ----------------
__global__ __launch_bounds__(256) void rms_kernel(const float* __restrict__ x,
                                                  const float* __restrict__ g,
                                                  bf16* __restrict__ out) {
    int s = blockIdx.x;
    const float4* row = (const float4*)(x + (size_t)s * DM);
    float4 v0 = row[threadIdx.x * 2];
    float4 v1 = row[threadIdx.x * 2 + 1];
    float ss = v0.x*v0.x + v0.y*v0.y + v0.z*v0.z + v0.w*v0.w
             + v1.x*v1.x + v1.y*v1.y + v1.z*v1.z + v1.w*v1.w;
    #pragma unroll
    for (int o = 32; o > 0; o >>= 1) ss += __shfl_down(ss, o, 64);
    __shared__ float red[4];
    if ((threadIdx.x & 63) == 0) red[threadIdx.x >> 6] = ss;
    __syncthreads();
    float total = red[0] + red[1] + red[2] + red[3];
    float inv = 1.0f / sqrtf(total / (float)DM + RMS_EPS);
    const float4* g4 = (const float4*)g;
    float4 ga = g4[threadIdx.x * 2], gb = g4[threadIdx.x * 2 + 1];
    union { bf16 h[8]; s8v v; } u;
    u.h[0] = __float2bfloat16(v0.x * inv * ga.x);
    u.h[1] = __float2bfloat16(v0.y * inv * ga.y);
    u.h[2] = __float2bfloat16(v0.z * inv * ga.z);
    u.h[3] = __float2bfloat16(v0.w * inv * ga.w);
    u.h[4] = __float2bfloat16(v1.x * inv * gb.x);
    u.h[5] = __float2bfloat16(v1.y * inv * gb.y);
    u.h[6] = __float2bfloat16(v1.z * inv * gb.z);
    u.h[7] = __float2bfloat16(v1.w * inv * gb.w);
    *(s8v*)(out + (size_t)s * DM + threadIdx.x * 8) = u.v;
}

// ---------------- bf16 MFMA GEMM with in-kernel f32-weight transpose (128x128x64) ----------------
template<bool OUTBF>
__global__ __launch_bounds__(256) void gemm_f32w_kernel(const bf16* __restrict__ A, int Ka,
                                                        const float* __restrict__ Wa, int Na,
                                                        const float* __restrict__ Wb, int Nb,
                                                        const float* __restrict__ Wc,
                                                        float* __restrict__ C,
                                                        bf16* __restrict__ Cb,
                                                        int M, int N, int Kchunk) {
    __shared__ bf16 As[2][128 * 64];
    __shared__ bf16 Bs[2][128 * 64];
    const int t = threadIdx.x, lane = t & 63;
    const int w = t >> 6;
    const int m0 = blockIdx.y * 128, n0 = blockIdx.x * 128;
    const size_t koff = (size_t)blockIdx.z * Kchunk;

    const int nl = t & 127;
    const int kob = t >> 7;
    const int ng = n0 + nl;
    const float* wp; int wstr;
    if (ng < Na)           { wp = Wa + ng;             wstr = Na; }
    else if (ng < Na + Nb) { wp = Wb + (ng - Na);      wstr = Nb; }
    else                   { wp = Wc + (ng - Na - Nb); wstr = N - Na - Nb; }
    wp += koff * (size_t)wstr;

    const int ako = t & 7, am = t >> 3;
    const bf16* apt = A + (size_t)(m0 + am) * Ka + koff + ako * 8;

    const int wm = (w >> 1) * 64, wn = (w & 1) * 64;
    const int fr = lane & 15, sl = lane >> 4;

    f32x4 acc[4][4];
    f32x4 z = {0.f, 0.f, 0.f, 0.f};
    #pragma unroll
    for (int i = 0; i < 4; ++i)
        #pragma unroll
        for (int j = 0; j < 4; ++j) acc[i][j] = z;

    float rb[4][8];
    s8v ra[4];

    auto LOADR = [&](int tile) {
        const int k0 = tile * 64;
        #pragma unroll
        for (int u = 0; u < 4; ++u) {
            const float* p = wp + (size_t)(k0 + (kob + 2 * u) * 8) * wstr;
            #pragma unroll
            for (int j = 0; j < 8; ++j) rb[u][j] = p[(size_t)j * wstr];
            ra[u] = *(const s8v*)(apt + (size_t)(32 * u) * Ka + k0);
        }
    };
    auto WRITE = [&](bf16* AsB, bf16* BsB) {
        #pragma unroll
        for (int u = 0; u < 4; ++u) {
            union { bf16 h[8]; s8v v; } cv;
            #pragma unroll
            for (int j = 0; j < 8; ++j) cv.h[j] = __float2bfloat16(rb[u][j]);
            int ko = kob + 2 * u;
            *(s8v*)((char*)BsB + nl * 128 + ((ko * 16) ^ ((nl & 7) << 4))) = cv.v;
            int m = am + 32 * u;
            *(s8v*)((char*)AsB + m * 128 + ((ako * 16) ^ ((m & 7) << 4))) = ra[u];
        }
    };
    auto COMPUTE = [&](const bf16* AsB, const bf16* BsB) {
        #pragma unroll
        for (int kk = 0; kk < 2; ++kk) {
            const int kb = kk * 64 + sl * 16;
            s8v af[4], bfv[4];
            #pragma unroll
            for (int i = 0; i < 4; ++i) {
                int m = wm + i * 16 + fr;
                af[i] = *(const s8v*)((const char*)AsB + m * 128 + (kb ^ ((m & 7) << 4)));
            }
            #pragma unroll
            for (int j = 0; j < 4; ++j) {
                int n = wn + j * 16 + fr;
                bfv[j] = *(const s8v*)((const char*)BsB + n * 128 + (kb ^ ((n & 7) << 4)));
            }
            #pragma unroll
            for (int i = 0; i < 4; ++i)
                #pragma unroll
                for (int j = 0; j < 4; ++j)
                    acc[i][j] = __builtin_amdgcn_mfma_f32_16x16x32_bf16(af[i], bfv[j], acc[i][j], 0, 0, 0);
        }
    };

    const int nt = Kchunk / 64;
    LOADR(0);
    WRITE(&As[0][0], &Bs[0][0]);
    __syncthreads();
    for (int tt = 0; tt < nt; ++tt) {
        const int cur = tt & 1;
        if (tt + 1 < nt) LOADR(tt + 1);
        COMPUTE(&As[cur][0], &Bs[cur][0]);
        if (tt + 1 < nt) {
            __syncthreads();
            WRITE(&As[cur ^ 1][0], &Bs[cur ^ 1][0]);
            __syncthreads();
        }
    }

    float* Cz = C + (size_t)blockIdx.z * M * N;
    #pragma unroll
    for (int i = 0; i < 4; ++i) {
        #pragma unroll
        for (int j = 0; j < 4; ++j) {
            #pragma unroll
            for (int q = 0; q < 4; ++q) {
                int row = m0 + wm + i * 16 + sl * 4 + q;
                int col = n0 + wn + j * 16 + fr;
                float vv = acc[i][j][q];
                if constexpr (OUTBF) Cb[(size_t)row * N + col] = __float2bfloat16(vv);
                else                 Cz[(size_t)row * N + col] = vv;
            }
        }
    }
}

// ---------------- 256x256x64 8-wave GEMM, f32 weights in, bf16 out (for gate|up) ----------------
__global__ __launch_bounds__(512) void gemm256_kernel(const bf16* __restrict__ A, int Ka,
                                                      const float* __restrict__ Wa, int Na,
                                                      const float* __restrict__ Wb,
                                                      bf16* __restrict__ Cb,
                                                      int M, int N, int K) {
    __shared__ bf16 As[2][256 * 64];
    __shared__ bf16 Bs[2][256 * 64];
    const int t = threadIdx.x, lane = t & 63;
    const int w = t >> 6;
    const int m0 = blockIdx.y * 256, n0 = blockIdx.x * 256;

    // B staging: thread owns column nl, k-octets kob+2u (u=0..3)
    const int nl = t & 255;
    const int kob = t >> 8;                 // 0 or 1
    const int ng = n0 + nl;
    const float* wp; int wstr;
    if (ng < Na) { wp = Wa + ng;        wstr = Na; }
    else         { wp = Wb + (ng - Na); wstr = N - Na; }

    // A staging: thread owns rows am+64u, k-octet ako
    const int ako = t & 7, am = t >> 3;     // am 0..63
    const bf16* apt = A + (size_t)(m0 + am) * Ka + ako * 8;

    // wave grid 2m x 4n; wave tile 128x64; frags 8m x 4n
    const int wm = (w >> 2) * 128, wn = (w & 3) * 64;
    const int fr = lane & 15, sl = lane >> 4;

    f32x4 acc[8][4];
    f32x4 z = {0.f, 0.f, 0.f, 0.f};
    #pragma unroll
    for (int i = 0; i < 8; ++i)
        #pragma unroll
        for (int j = 0; j < 4; ++j) acc[i][j] = z;

    float rb[4][8];
    s8v ra[4];

    auto LOADR = [&](int tile) {
        const int k0 = tile * 64;
        #pragma unroll
        for (int u = 0; u < 4; ++u) {
            const float* p = wp + (size_t)(k0 + (kob + 2 * u) * 8) * wstr;
            #pragma unroll
            for (int j = 0; j < 8; ++j) rb[u][j] = p[(size_t)j * wstr];
            ra[u] = *(const s8v*)(apt + (size_t)(64 * u) * Ka + k0);
        }
    };
    auto WRITE = [&](bf16* AsB, bf16* BsB) {
        #pragma unroll
        for (int u = 0; u < 4; ++u) {
            union { bf16 h[8]; s8v v; } cv;
            #pragma unroll
            for (int j = 0; j < 8; ++j) cv.h[j] = __float2bfloat16(rb[u][j]);
            int ko = kob + 2 * u;
            *(s8v*)((char*)BsB + nl * 128 + ((ko * 16) ^ ((nl & 7) << 4))) = cv.v;
            int m = am + 64 * u;
            *(s8v*)((char*)AsB + m * 128 + ((ako * 16) ^ ((m & 7) << 4))) = ra[u];
        }
    };
    auto COMPUTE = [&](const bf16* AsB, const bf16* BsB) {
        #pragma unroll
        for (int kk = 0; kk < 2; ++kk) {
            const int kb = kk * 64 + sl * 16;
            s8v af[8], bfv[4];
            #pragma unroll
            for (int i = 0; i < 8; ++i) {
                int m = wm + i * 16 + fr;
                af[i] = *(const s8v*)((const char*)AsB + m * 128 + (kb ^ ((m & 7) << 4)));
            }
            #pragma unroll
            for (int j = 0; j < 4; ++j) {
                int n = wn + j * 16 + fr;
                bfv[j] = *(const s8v*)((const char*)BsB + n * 128 + (kb ^ ((n & 7) << 4)));
            }
            #pragma unroll
            for (int i = 0; i < 8; ++i)
                #pragma unroll
                for (int j = 0; j < 4; ++j)
                    acc[i][j] = __builtin_amdgcn_mfma_f32_16x16x32_bf16(af[i], bfv[j], acc[i][j], 0, 0, 0);
        }
    };

    const int nt = K / 64;
    LOADR(0);
    WRITE(&As[0][0], &Bs[0][0]);
    __syncthreads();
    for (int tt = 0; tt < nt; ++tt) {
        const int cur = tt & 1;
        if (tt + 1 < nt) LOADR(tt + 1);
        COMPUTE(&As[cur][0], &Bs[cur][0]);
        if (tt + 1 < nt) {
            __syncthreads();
            WRITE(&As[cur ^ 1][0], &Bs[cur ^ 1][0]);
            __syncthreads();
        }
    }

    #pragma unroll
    for (int i = 0; i < 8; ++i) {
        #pragma unroll
        for (int j = 0; j < 4; ++j) {
            #pragma unroll
            for (int q = 0; q < 4; ++q) {
                int row = m0 + wm + i * 16 + sl * 4 + q;
                int col = n0 + wn + j * 16 + fr;
                Cb[(size_t)row * N + col] = __float2bfloat16(acc[i][j][q]);
            }
        }
    }
}

// ---------------- split-K reduce: x += p0+p1+p2+p3 ----------------
__global__ __launch_bounds__(256) void reduce4_kernel(float* __restrict__ x,
                                                      const float* __restrict__ p) {
    const int n4 = SEQ * DM / 4;
    int i = blockIdx.x * 256 + threadIdx.x;
    if (i >= n4) return;
    float4 a = ((const float4*)x)[i];
    #pragma unroll
    for (int c = 0; c < 4; ++c) {
        float4 v = ((const float4*)p)[i + c * n4];
        a.x += v.x; a.y += v.y; a.z += v.z; a.w += v.w;
    }
    ((float4*)x)[i] = a;
}

// ---------------- RoPE: f32 qkv -> bf16 Qh[h][s][d], Kh[kvh][s][d] ----------------
__global__ __launch_bounds__(256) void rope_qk_kernel(const float* __restrict__ qkv,
                                                      bf16* __restrict__ Qh,
                                                      bf16* __restrict__ Kh) {
    int idx = blockIdx.x * 256 + threadIdx.x;
    int i = idx & 31;
    int hh = (idx >> 5) % (NH + NKVH);
    int s = idx / (32 * (NH + NKVH));
    bool isq = hh < NH;
    int col = isq ? hh * HD + i : DM + (hh - NH) * HD + i;
    float a = qkv[(size_t)s * QKVW + col];
    float b = qkv[(size_t)s * QKVW + col + 32];
    float inv = exp2f(-(float)i * 0.41524101186092029f);
    float ang = (float)s * inv;
    float c = cosf(ang), sn = sinf(ang);
    float ra = a * c - b * sn;
    float rb = b * c + a * sn;
    if (isq) {
        bf16* p = Qh + ((size_t)hh * SEQ + s) * HD + i;
        p[0]  = __float2bfloat16(ra);
        p[32] = __float2bfloat16(rb);
    } else {
        bf16* p = Kh + ((size_t)(hh - NH) * SEQ + s) * HD + i;
        p[0]  = __float2bfloat16(ra);
        p[32] = __float2bfloat16(rb);
    }
}

// ---------------- V transpose: f32 qkv -> bf16 Vt[kvh][d][s] ----------------
__global__ __launch_bounds__(256) void vtrans_kernel(const float* __restrict__ qkv,
                                                     bf16* __restrict__ Vt) {
    __shared__ float tile[64][65];
    const int s0 = blockIdx.x * 64;
    const int kvh = blockIdx.y;
    const int tx = threadIdx.x & 63, ty = threadIdx.x >> 6;
    #pragma unroll
    for (int i = 0; i < 16; ++i)
        tile[i * 4 + ty][tx] = qkv[(size_t)(s0 + i * 4 + ty) * QKVW + DM + 512 + kvh * HD + tx];
    __syncthreads();
    #pragma unroll
    for (int i = 0; i < 16; ++i) {
        int d = i * 4 + ty;
        Vt[((size_t)kvh * HD + d) * SEQ + s0 + tx] = __float2bfloat16(tile[tx][d]);
    }
}

// ---------------- MFMA flash attention: 4 waves x 16-row strips, KVBLK=64 ----------------
__global__ __launch_bounds__(256) void attn_mfma_kernel(const bf16* __restrict__ Qh,
                                                        const bf16* __restrict__ Kh,
                                                        const bf16* __restrict__ Vt,
                                                        bf16* __restrict__ o) {
    __shared__ char lds[32768];
    char* Qs = lds;
    char* Ks = lds + 8192;
    char* Vs = lds + 16384;
    char* Ps = lds + 24576;
    const int t = threadIdx.x, lane = t & 63, w = t >> 6;
    const int g = lane >> 4, lo = lane & 15;
    const int h = blockIdx.y, kvh = h >> 2;
    const int qbase = blockIdx.x * 64;
    const int strip = w * 16;
    const bf16* qsrc = Qh + ((size_t)h * SEQ + qbase) * HD;
    const bf16* ksrc = Kh + (size_t)kvh * SEQ * HD;
    const bf16* vsrc = Vt + (size_t)kvh * HD * SEQ;

    #pragma unroll
    for (int c = t; c < 512; c += 256) {
        int row = c >> 3, col = c & 7;
        *(s8v*)(Qs + row * 128 + ((col * 16) ^ ((row & 7) << 4))) =
            *(const s8v*)(qsrc + row * HD + col * 8);
    }

    f32x4 oacc[4];
    f32x4 z = {0.f, 0.f, 0.f, 0.f};
    #pragma unroll
    for (int dj = 0; dj < 4; ++dj) oacc[dj] = z;
    float m0[4], lsum[4];
    #pragma unroll
    for (int r = 0; r < 4; ++r) { m0[r] = -INFINITY; lsum[r] = 0.f; }

    const int qt = blockIdx.x;
    for (int kt = 0; kt <= qt; ++kt) {
        __syncthreads();
        const bf16* kq = ksrc + (size_t)(kt * 64) * HD;
        const bf16* vq = vsrc + kt * 64;
        #pragma unroll
        for (int c = t; c < 512; c += 256) {
            int row = c >> 3, col = c & 7;
            int swz = (col * 16) ^ ((row & 7) << 4);
            *(s8v*)(Ks + row * 128 + swz) = *(const s8v*)(kq + row * HD + col * 8);
            *(s8v*)(Vs + row * 128 + swz) = *(const s8v*)(vq + (size_t)row * SEQ + col * 8);
        }
        __syncthreads();

        s8v qa0 = *(const s8v*)(Qs + (strip + lo) * 128 + ((g * 16) ^ ((lo & 7) << 4)));
        s8v qa1 = *(const s8v*)(Qs + (strip + lo) * 128 + ((64 + g * 16) ^ ((lo & 7) << 4)));
        f32x4 sacc[4];
        #pragma unroll
        for (int j = 0; j < 4; ++j) {
            s8v kb0 = *(const s8v*)(Ks + (j * 16 + lo) * 128 + ((g * 16) ^ ((lo & 7) << 4)));
            s8v kb1 = *(const s8v*)(Ks + (j * 16 + lo) * 128 + ((64 + g * 16) ^ ((lo & 7) << 4)));
            f32x4 sv = __builtin_amdgcn_mfma_f32_16x16x32_bf16(qa0, kb0, z, 0, 0, 0);
            sacc[j] = __builtin_amdgcn_mfma_f32_16x16x32_bf16(qa1, kb1, sv, 0, 0, 0);
        }
        #pragma unroll
        for (int j = 0; j < 4; ++j) {
            int kgl = kt * 64 + j * 16 + lo;
            #pragma unroll
            for (int r = 0; r < 4; ++r) {
                int qgl = qbase + strip + g * 4 + r;
                float sv = sacc[j][r] * 0.125f;
                sacc[j][r] = (kgl <= qgl) ? sv : -INFINITY;
            }
        }
        float rmax[4], resc[4];
        #pragma unroll
        for (int r = 0; r < 4; ++r) {
            float mx = fmaxf(fmaxf(sacc[0][r], sacc[1][r]), fmaxf(sacc[2][r], sacc[3][r]));
            mx = fmaxf(mx, __shfl_xor(mx, 1, 64));
            mx = fmaxf(mx, __shfl_xor(mx, 2, 64));
            mx = fmaxf(mx, __shfl_xor(mx, 4, 64));
            mx = fmaxf(mx, __shfl_xor(mx, 8, 64));
            float mn = fmaxf(m0[r], mx);
            resc[r] = expf(m0[r] - mn);
            m0[r] = mn;
            rmax[r] = mn;
        }
        #pragma unroll
        for (int j = 0; j < 4; ++j)
            #pragma unroll
            for (int r = 0; r < 4; ++r)
                sacc[j][r] = expf(sacc[j][r] - rmax[r]);
        #pragma unroll
        for (int r = 0; r < 4; ++r) {
            float ps = sacc[0][r] + sacc[1][r] + sacc[2][r] + sacc[3][r];
            lsum[r] = lsum[r] * resc[r] + ps;
        }
        #pragma unroll
        for (int dj = 0; dj < 4; ++dj)
            #pragma unroll
            for (int r = 0; r < 4; ++r)
                oacc[dj][r] *= resc[r];
        #pragma unroll
        for (int j = 0; j < 4; ++j) {
            #pragma unroll
            for (int r = 0; r < 4; ++r) {
                int prow = strip + g * 4 + r;
                int pcol = j * 16 + lo;
                *(bf16*)(Ps + prow * 128 + ((pcol * 2) ^ ((prow & 7) << 4))) =
                    __float2bfloat16(sacc[j][r]);
            }
        }
        s8v pa0 = *(const s8v*)(Ps + (strip + lo) * 128 + ((g * 16) ^ ((lo & 7) << 4)));
        s8v pa1 = *(const s8v*)(Ps + (strip + lo) * 128 + ((64 + g * 16) ^ ((lo & 7) << 4)));
        #pragma unroll
        for (int dj = 0; dj < 4; ++dj) {
            s8v vb0 = *(const s8v*)(Vs + (dj * 16 + lo) * 128 + ((g * 16) ^ ((lo & 7) << 4)));
            s8v vb1 = *(const s8v*)(Vs + (dj * 16 + lo) * 128 + ((64 + g * 16) ^ ((lo & 7) << 4)));
            oacc[dj] = __builtin_amdgcn_mfma_f32_16x16x32_bf16(pa0, vb0, oacc[dj], 0, 0, 0);
            oacc[dj] = __builtin_amdgcn_mfma_f32_16x16x32_bf16(pa1, vb1, oacc[dj], 0, 0, 0);
        }
    }
    float invl[4];
    #pragma unroll
    for (int r = 0; r < 4; ++r) {
        float l = lsum[r];
        l += __shfl_xor(l, 1, 64);
        l += __shfl_xor(l, 2, 64);
        l += __shfl_xor(l, 4, 64);
        l += __shfl_xor(l, 8, 64);
        invl[r] = 1.f / l;
    }
    #pragma unroll
    for (int dj = 0; dj < 4; ++dj) {
        #pragma unroll
        for (int r = 0; r < 4; ++r) {
            int qrow = qbase + strip + g * 4 + r;
            o[(size_t)qrow * DM + h * HD + dj * 16 + lo] =
                __float2bfloat16(oacc[dj][r] * invl[r]);
        }
    }
}

// ---------------- silu(gate)*up from fused bf16 gu buffer -> bf16 ----------------
__global__ __launch_bounds__(256) void silu_mul_kernel(const bf16* __restrict__ gu,
                                                       bf16* __restrict__ ga) {
    int i = blockIdx.x * 256 + threadIdx.x;
    int s = i >> 10;
    int c8 = i & 1023;
    union { s8v v; bf16 h[8]; } gv, uv, ov;
    gv.v = *(const s8v*)(gu + (size_t)s * (2 * FF) + c8 * 8);
    uv.v = *(const s8v*)(gu + (size_t)s * (2 * FF) + FF + c8 * 8);
    #pragma unroll
    for (int j = 0; j < 8; ++j) {
        float g = __bfloat162float(gv.h[j]);
        float u = __bfloat162float(uv.h[j]);
        ov.h[j] = __float2bfloat16(g / (1.f + expf(-g)) * u);
    }
    *(s8v*)(ga + (size_t)s * FF + c8 * 8) = ov.v;
}

extern "C" void kernel_launch(void* const* d_in, const int* in_sizes, int n_in,
                              void* d_out, int out_size, void* d_ws, size_t ws_size,
                              hipStream_t stream) {
    const int*   ids   = (const int*)d_in[0];
    const float* emb   = (const float*)d_in[1];
    const float* wq    = (const float*)d_in[2];
    const float* wk    = (const float*)d_in[3];
    const float* wv    = (const float*)d_in[4];
    const float* wo    = (const float*)d_in[5];
    const float* wgate = (const float*)d_in[6];
    const float* wup   = (const float*)d_in[7];
    const float* wdown = (const float*)d_in[8];
    const float* ln1   = (const float*)d_in[9];
    const float* ln2   = (const float*)d_in[10];
    float* x = (float*)d_out;

    bf16* h_bf  = (bf16*)d_ws;
    bf16* attnb = h_bf  + (size_t)SEQ * DM;
    bf16* gub   = attnb + (size_t)SEQ * DM;
    bf16* gab   = gub   + (size_t)SEQ * 2 * FF;
    bf16* Qhb   = gab   + (size_t)SEQ * FF;
    bf16* Khb   = Qhb   + (size_t)NH * SEQ * HD;
    bf16* Vtb   = Khb   + (size_t)NKVH * SEQ * HD;
    float* qkv  = (float*)(Vtb + (size_t)NKVH * HD * SEQ);
    float* psum = qkv + (size_t)SEQ * QKVW;

    embed_kernel<<<SEQ, 256, 0, stream>>>(ids, emb, x);

    for (int l = 0; l < NL; ++l) {
        const float* wq_l = wq + (size_t)l * DM * DM;
        const float* wk_l = wk + (size_t)l * DM * 512;
        const float* wv_l = wv + (size_t)l * DM * 512;
        const float* wo_l = wo + (size_t)l * DM * DM;
        const float* wg_l = wgate + (size_t)l * DM * FF;
        const float* wu_l = wup   + (size_t)l * DM * FF;
        const float* wd_l = wdown + (size_t)l * FF * DM;

        rms_kernel<<<SEQ, 256, 0, stream>>>(x, ln1 + (size_t)l * DM, h_bf);

        // qkv: fused wq|wk|wv, M=1024 N=3072 K=2048 -> f32
        gemm_f32w_kernel<false><<<dim3(QKVW / 128, SEQ / 128, 1), 256, 0, stream>>>(
            h_bf, DM, wq_l, DM, wk_l, 512, wv_l, qkv, nullptr, SEQ, QKVW, DM);

        rope_qk_kernel<<<(SEQ * (NH + NKVH) * 32) / 256, 256, 0, stream>>>(qkv, Qhb, Khb);
        vtrans_kernel<<<dim3(SEQ / 64, NKVH), 256, 0, stream>>>(qkv, Vtb);

        attn_mfma_kernel<<<dim3(SEQ / 64, NH), 256, 0, stream>>>(Qhb, Khb, Vtb, attnb);

        // wo: M=1024 N=2048 K=2048, split-K x4 -> psum; x += sum(psum)
        gemm_f32w_kernel<false><<<dim3(DM / 128, SEQ / 128, 4), 256, 0, stream>>>(
            attnb, DM, wo_l, DM, nullptr, 0, nullptr, psum, nullptr, SEQ, DM, DM / 4);
        reduce4_kernel<<<(SEQ * DM / 4) / 256, 256, 0, stream>>>(x, psum);

        rms_kernel<<<SEQ, 256, 0, stream>>>(x, ln2 + (size_t)l * DM, h_bf);

        // gate|up: fused wgate|wup, M=1024 N=16384 K=2048 -> bf16 (256x256 8-wave kernel)
        gemm256_kernel<<<dim3((2 * FF) / 256, SEQ / 256), 512, 0, stream>>>(
            h_bf, DM, wg_l, FF, wu_l, gub, SEQ, 2 * FF, DM);

        silu_mul_kernel<<<(SEQ * FF / 8) / 256, 256, 0, stream>>>(gub, gab);

        // down: M=1024 N=2048 K=8192, split-K x4 -> psum; x += sum(psum)
        gemm_f32w_kernel<false><<<dim3(DM / 128, SEQ / 128, 4), 256, 0, stream>>>(
            gab, FF, wd_l, DM, nullptr, 0, nullptr, psum, nullptr, SEQ, DM, FF / 4);
        reduce4_kernel<<<(SEQ * DM / 4) / 256, 256, 0, stream>>>(x, psum);
    }
}